// Round 3
// baseline (128.772 us; speedup 1.0000x reference)
//
#include <hip/hip_runtime.h>
#include <stdint.h>

#define NQ   12
#define DIM  4096   // 2^12 amplitudes
#define TPB  256

typedef float v2f __attribute__((ext_vector_type(2)));
typedef float v4f __attribute__((ext_vector_type(4)));

// ---------- compile-time GF(2) circuit structure ----------
struct PassP {
  uint16_t v[4];     // pair XOR-vectors (columns of A^-k)
  uint16_t m[4];     // role parity masks (rows of A^k)
  uint16_t cmb[16];  // cmb[n] = XOR of v[i] over set bits of n
  uint8_t  np[8];    // free-bit positions (thread-bit k -> index bit np[k])
  uint8_t  layer;    // qparams layer (1 or 2)
  uint8_t  wbase;    // first wire of this group of 4
};
struct KP {
  PassP    pass[6];
  uint16_t ro_mask[12]; // rows of A^3 (readout parity masks)
  uint8_t  ro_bin[12];  // WHT bin per qubit over pass-5 coset directions
};

constexpr int chbit(uint32_t x) { int b = -1; for (int i = 0; i < 32; ++i) if ((x >> i) & 1u) b = i; return b; }

constexpr void bmm(uint32_t* C, const uint32_t* A, const uint32_t* B) {
  for (int i = 0; i < NQ; ++i) {
    uint32_t r = 0;
    for (int j = 0; j < NQ; ++j) if ((A[i] >> j) & 1u) r ^= B[j];
    C[i] = r;
  }
}
constexpr void binv(const uint32_t* M, uint32_t* Inv) {
  uint32_t A[NQ] = {}, I[NQ] = {};
  for (int i = 0; i < NQ; ++i) { A[i] = M[i]; I[i] = 1u << i; }
  for (int c = 0; c < NQ; ++c) {
    int piv = -1;
    for (int r = c; r < NQ; ++r) if ((A[r] >> c) & 1u) { piv = r; break; }
    if (piv < 0) continue;
    uint32_t ta = A[c]; A[c] = A[piv]; A[piv] = ta;
    uint32_t ti = I[c]; I[c] = I[piv]; I[piv] = ti;
    for (int r = 0; r < NQ; ++r)
      if (r != c && ((A[r] >> c) & 1u)) { A[r] ^= A[c]; I[r] ^= I[c]; }
  }
  for (int i = 0; i < NQ; ++i) Inv[i] = I[i];
}

constexpr KP make_kp() {
  KP kp{};
  // CNOT chain: q[i+1]^=q[i] for i=0..10, then q[0]^=q[11]
  uint32_t A[NQ] = {};
  A[0] = 0xFFEu;
  for (int i = 1; i < NQ; ++i) A[i] = (1u << (i + 1)) - 1u;
  uint32_t A2[NQ] = {}, A3[NQ] = {}, Ai[NQ] = {}, A2i[NQ] = {};
  bmm(A2, A, A); bmm(A3, A2, A);
  binv(A, Ai); binv(A2, A2i);

  for (int p = 0; p < 6; ++p) {
    int L = (p < 3) ? 1 : 2;
    int wb = (p % 3) * 4;
    const uint32_t* M  = (L == 1) ? A  : A2;
    const uint32_t* Mi = (L == 1) ? Ai : A2i;
    uint32_t v[4] = {}, m[4] = {};
    for (int i = 0; i < 4; ++i) {
      int w = wb + i;
      uint32_t col = 0;
      for (int r = 0; r < NQ; ++r) col |= ((Mi[r] >> w) & 1u) << r;
      v[i] = col; m[i] = M[w];
    }
    // pivot bits of span{v} -> 8 free (non-pivot) bit positions
    uint32_t redv[4] = {}; int pbit[4] = {}; uint32_t pivmask = 0;
    for (int i = 0; i < 4; ++i) {
      redv[i] = v[i];
      for (int k = 0; k < i; ++k) if ((redv[i] >> pbit[k]) & 1u) redv[i] ^= redv[k];
      pbit[i] = chbit(redv[i]);
      pivmask |= 1u << pbit[i];
    }
    uint8_t np0[8] = {};
    int c = 0;
    for (int b = 0; b < NQ; ++b)
      if (!((pivmask >> b) & 1u)) np0[c++] = (uint8_t)b;

    // bank-conflict-aware ordering: low-4 rows of B=I^sum v_i m_i^T restricted
    // to {np[0..3]} must be rank-4 so lanes 0..15 hit distinct (addr&15).
    uint32_t Brow[4] = {};
    for (int r = 0; r < 4; ++r) {
      uint32_t row = 1u << r;
      for (int i = 0; i < 4; ++i) if ((v[i] >> r) & 1u) row ^= m[i];
      Brow[r] = row;
    }
    uint32_t colsig[8] = {};
    for (int cc = 0; cc < 8; ++cc) {
      uint32_t s = 0;
      for (int r = 0; r < 4; ++r) s |= ((Brow[r] >> np0[cc]) & 1u) << r;
      colsig[cc] = s;
    }
    int b0 = 0, b1 = 1, b2 = 2, b3 = 3, bestrank = -1;
    bool found = false;
    for (int a = 0; a < 8 && !found; ++a)
      for (int b = a + 1; b < 8 && !found; ++b)
        for (int cx = b + 1; cx < 8 && !found; ++cx)
          for (int d = cx + 1; d < 8 && !found; ++d) {
            uint32_t rows2[4] = {}; int rnk = 0;
            int idxs[4] = {a, b, cx, d};
            for (int q = 0; q < 4; ++q) {
              uint32_t xx = colsig[idxs[q]];
              for (int bit = 3; bit >= 0; --bit) {
                if (!((xx >> bit) & 1u)) continue;
                if (rows2[bit]) { xx ^= rows2[bit]; }
                else { rows2[bit] = xx; ++rnk; break; }
              }
            }
            if (rnk > bestrank) {
              bestrank = rnk; b0 = a; b1 = b; b2 = cx; b3 = d;
              if (rnk == 4) found = true;
            }
          }
    uint8_t npn[8] = {};
    npn[0] = np0[b0]; npn[1] = np0[b1]; npn[2] = np0[b2]; npn[3] = np0[b3];
    int cn = 4;
    for (int cc = 0; cc < 8; ++cc)
      if (cc != b0 && cc != b1 && cc != b2 && cc != b3) npn[cn++] = np0[cc];
    for (int cc = 0; cc < 8; ++cc) kp.pass[p].np[cc] = npn[cc];

    for (int n = 0; n < 16; ++n) {
      uint32_t cm = 0;
      for (int i = 0; i < 4; ++i) if ((n >> i) & 1) cm ^= v[i];
      kp.pass[p].cmb[n] = (uint16_t)cm;
    }
    for (int i = 0; i < 4; ++i) { kp.pass[p].v[i] = (uint16_t)v[i]; kp.pass[p].m[i] = (uint16_t)m[i]; }
    kp.pass[p].layer = (uint8_t)L; kp.pass[p].wbase = (uint8_t)wb;
  }
  for (int i = 0; i < NQ; ++i) kp.ro_mask[i] = (uint16_t)A3[i];
  for (int i = 0; i < NQ; ++i) {
    uint32_t b = 0;
    for (int j = 0; j < 4; ++j)
      b |= (uint32_t)(__builtin_popcount(A3[i] & (uint32_t)kp.pass[5].v[j]) & 1) << j;
    kp.ro_bin[i] = (uint8_t)b;
  }
  return kp;
}

constexpr KP kpc = make_kp();

// ---------- device helpers ----------
__device__ __forceinline__ void build_u(const float* __restrict__ qp, int l, int w, float U[8]) {
  float p0 = qp[(l * 12 + w) * 3 + 0];
  float p1 = qp[(l * 12 + w) * 3 + 1];
  float p2 = qp[(l * 12 + w) * 3 + 2];
  float cx, sx, cy, sy, cz, sz;
  sincosf(0.5f * p0, &sx, &cx);
  sincosf(0.5f * p1, &sy, &cy);
  sincosf(0.5f * p2, &sz, &cz);
  float M00x =  cy * cx, M00y =  sy * sx;
  float M01x = -sy * cx, M01y = -cy * sx;
  float M10x =  sy * cx, M10y = -cy * sx;
  float M11x =  cy * cx, M11y = -sy * sx;
  U[0] = cz * M00x + sz * M00y; U[1] = cz * M00y - sz * M00x;
  U[2] = cz * M01x + sz * M01y; U[3] = cz * M01y - sz * M01x;
  U[4] = cz * M10x - sz * M10y; U[5] = cz * M10y + sz * M10x;
  U[6] = cz * M11x - sz * M11y; U[7] = cz * M11y + sz * M11x;
}

template<int P>
__device__ __forceinline__ int pass_base(int t) {
  int rep = 0;
  #pragma unroll
  for (int k = 0; k < 8; ++k) rep |= ((t >> k) & 1) << kpc.pass[P].np[k];
  int rho = 0;
  #pragma unroll
  for (int i = 0; i < 4; ++i) rho |= (__popc(kpc.pass[P].m[i] & rep) & 1) << i;
  int base = rep;
  #pragma unroll
  for (int i = 0; i < 4; ++i) if ((rho >> i) & 1) base ^= kpc.pass[P].v[i];
  return base;
}

template<int P>
__device__ __forceinline__ void pass_load(const v2f* stx, int base, v2f sl[16]) {
  #pragma unroll
  for (int r = 0; r < 16; ++r) sl[r] = stx[base ^ kpc.pass[P].cmb[r]];
}

template<int P>
__device__ __forceinline__ void pass_store(v2f* stx, int base, const v2f sl[16]) {
  #pragma unroll
  for (int r = 0; r < 16; ++r) stx[base ^ kpc.pass[P].cmb[r]] = sl[r];
}

template<int P>
__device__ __forceinline__ void pass_chew(const v4f (*gp)[4], v2f sl[16]) {
  constexpr int wb = kpc.pass[P].wbase;
  #pragma unroll
  for (int i = 0; i < 4; ++i) {
    v4f gA = gp[wb + i][0], gB = gp[wb + i][1];
    v4f gC = gp[wb + i][2], gD = gp[wb + i][3];
    #pragma unroll
    for (int r = 0; r < 16; ++r) {
      if (r & (1 << i)) continue;
      int r1 = r | (1 << i);
      v2f a0 = sl[r], a1 = sl[r1];
      v2f a0s = a0.yx, a1s = a1.yx;
      sl[r]  = gA.xy * a0 + gA.zw * a0s + gB.xy * a1 + gB.zw * a1s;
      sl[r1] = gC.xy * a0 + gC.zw * a0s + gD.xy * a1 + gD.zw * a1s;
    }
  }
}

__device__ __forceinline__ void readout_ev(const v2f sl[16], int base, float ev[NQ]) {
  float pr[16];
  #pragma unroll
  for (int r = 0; r < 16; ++r) pr[r] = sl[r].x * sl[r].x + sl[r].y * sl[r].y;
  #pragma unroll
  for (int g = 1; g < 16; g <<= 1) {
    #pragma unroll
    for (int j = 0; j < 16; ++j) {
      if (j & g) continue;
      float u = pr[j], w2 = pr[j | g];
      pr[j] = u + w2; pr[j | g] = u - w2;
    }
  }
  #pragma unroll
  for (int i = 0; i < NQ; ++i) {
    float h = pr[kpc.ro_bin[i]];
    int sgn = (__popc((int)kpc.ro_mask[i] & base) & 1) << 31;
    ev[i] = __int_as_float(__float_as_int(h) ^ sgn);
  }
}

__device__ __forceinline__ void wave_reduce(float ev[NQ]) {
  #pragma unroll
  for (int off = 32; off >= 1; off >>= 1) {
    #pragma unroll
    for (int i = 0; i < NQ; ++i) ev[i] += __shfl_xor(ev[i], off, 64);
  }
}

// ---------- kernel: 2 samples per block, staggered phases ----------
__global__ __launch_bounds__(TPB, 2) void hqc_kernel(
    const float* __restrict__ x,  const float* __restrict__ W1, const float* __restrict__ b1,
    const float* __restrict__ W2, const float* __restrict__ b2,
    const float* __restrict__ W3, const float* __restrict__ b3,
    const float* __restrict__ qp, const float* __restrict__ P1, const float* __restrict__ c1,
    const float* __restrict__ P2, const float* __restrict__ c2,
    const float* __restrict__ P3, const float* __restrict__ c3,
    float* __restrict__ out)
{
  __shared__ v2f  st[2][DIM];          // 64 KB: two statevectors
  __shared__ v4f  gpk[3][2][NQ][4];    // gates packed {x,x,-y,y} per entry
  __shared__ float red[2][4][NQ];      // per-wave readout partials

  const int t    = threadIdx.x;
  const int lane = t & 63;
  const int wv   = t >> 6;
  const int s0   = blockIdx.x * 2;

  // ---- phase 0: wave 0/1 = MLP + L0 gates (sample A/B); wave 2/3 = L1/L2 gates ----
  if (wv < 2) {
    const int s = s0 + wv;
    if (lane < 16) {
      float a = b1[lane];
      #pragma unroll
      for (int k = 0; k < 6; ++k) a = fmaf(W1[lane * 6 + k], x[s * 6 + k], a);
      float h1 = fmaxf(a, 0.f);
      float a2 = b2[lane];
      #pragma unroll
      for (int k = 0; k < 16; ++k) a2 = fmaf(W2[lane * 16 + k], __shfl(h1, k, 64), a2);
      float h2 = fmaxf(a2, 0.f);
      const int lw = (lane < NQ) ? lane : 0;
      float a3 = b3[lw];
      #pragma unroll
      for (int k = 0; k < 16; ++k) a3 = fmaf(W3[lw * 16 + k], __shfl(h2, k, 64), a3);
      if (lane < NQ) {
        float U[8]; build_u(qp, 0, lane, U);
        float ca, sa; sincosf(0.5f * a3, &sa, &ca);
        float c0x = U[0] * ca + U[2] * sa, c0y = U[1] * ca + U[3] * sa;
        float c1x = U[4] * ca + U[6] * sa, c1y = U[5] * ca + U[7] * sa;
        gpk[0][wv][lane][0] = (v4f){c0x, c0x, -c0y, c0y};
        gpk[0][wv][lane][1] = (v4f){c1x, c1x, -c1y, c1y};
      }
    }
  } else {
    const int L = wv - 1;  // 1 or 2
    if (lane < 24) {
      const int ss = lane / 12, w = lane % 12;
      float U[8]; build_u(qp, L, w, U);
      gpk[L][ss][w][0] = (v4f){U[0], U[0], -U[1], U[1]};
      gpk[L][ss][w][1] = (v4f){U[2], U[2], -U[3], U[3]};
      gpk[L][ss][w][2] = (v4f){U[4], U[4], -U[5], U[5]};
      gpk[L][ss][w][3] = (v4f){U[6], U[6], -U[7], U[7]};
    }
  }
  __syncthreads();

  // ---- product-state init for both samples ----
  #pragma unroll
  for (int sm = 0; sm < 2; ++sm) {
    v2f acc = (v2f){1.f, 0.f};
    #pragma unroll
    for (int i = 0; i < 8; ++i) {
      v4f g = gpk[0][sm][i][(t >> i) & 1];
      acc = g.xy * acc + g.zw * acc.yx;
    }
    v2f l16[16];
    l16[0] = acc;
    #pragma unroll
    for (int i = 0; i < 4; ++i) {
      v4f g0 = gpk[0][sm][8 + i][0], g1 = gpk[0][sm][8 + i][1];
      #pragma unroll
      for (int j = 0; j < (1 << i); ++j) {
        v2f a = l16[j];
        l16[j | (1 << i)] = g1.xy * a + g1.zw * a.yx;
        l16[j]            = g0.xy * a + g0.zw * a.yx;
      }
    }
    #pragma unroll
    for (int j = 0; j < 16; ++j) st[sm][t | (j << 8)] = l16[j];
  }
  __syncthreads();

  // ---- passes 0..4: load both, chew/store staggered, one barrier each ----
  #define DO_PASS(P)                                            \
  {                                                             \
    constexpr int L = kpc.pass[P].layer;                        \
    const int base = pass_base<P>(t);                           \
    v2f slA[16], slB[16];                                       \
    pass_load<P>(st[0], base, slA);                             \
    pass_load<P>(st[1], base, slB);                             \
    pass_chew<P>(gpk[L][0], slA);                               \
    pass_store<P>(st[0], base, slA);                            \
    pass_chew<P>(gpk[L][1], slB);                               \
    pass_store<P>(st[1], base, slB);                            \
    __syncthreads();                                            \
  }
  DO_PASS(0)
  DO_PASS(1)
  DO_PASS(2)
  DO_PASS(3)
  DO_PASS(4)
  #undef DO_PASS

  // ---- pass 5 with fused readout (no final store/reload) ----
  {
    const int base = pass_base<5>(t);
    v2f slA[16], slB[16];
    pass_load<5>(st[0], base, slA);
    pass_load<5>(st[1], base, slB);
    pass_chew<5>(gpk[2][0], slA);
    float evA[NQ];
    readout_ev(slA, base, evA);
    wave_reduce(evA);
    if (lane == 0) {
      #pragma unroll
      for (int i = 0; i < NQ; ++i) red[0][wv][i] = evA[i];
    }
    pass_chew<5>(gpk[2][1], slB);
    float evB[NQ];
    readout_ev(slB, base, evB);
    wave_reduce(evB);
    if (lane == 0) {
      #pragma unroll
      for (int i = 0; i < NQ; ++i) red[1][wv][i] = evB[i];
    }
  }
  __syncthreads();

  // ---- post-MLP: wave 0 -> sample A, wave 1 -> sample B, shuffle-based ----
  if (wv < 2) {
    const int sm = wv;
    if (lane < 16) {
      float q = (lane < NQ)
        ? (red[sm][0][lane] + red[sm][1][lane] + red[sm][2][lane] + red[sm][3][lane])
        : 0.f;
      float a = c1[lane];
      #pragma unroll
      for (int j = 0; j < NQ; ++j) a = fmaf(P1[lane * NQ + j], __shfl(q, j, 64), a);
      float o1 = fmaxf(a, 0.f);
      float a2 = c2[lane & 7];
      #pragma unroll
      for (int j = 0; j < 16; ++j) a2 = fmaf(P2[(lane & 7) * 16 + j], __shfl(o1, j, 64), a2);
      float o2 = fmaxf(a2, 0.f);
      float a3 = c3[0];
      #pragma unroll
      for (int j = 0; j < 8; ++j) a3 = fmaf(P3[j], __shfl(o2, j, 64), a3);
      if (lane == 0) out[s0 + sm] = 1.f / (1.f + expf(-a3));
    }
  }
}

extern "C" void kernel_launch(void* const* d_in, const int* in_sizes, int n_in,
                              void* d_out, int out_size, void* d_ws, size_t ws_size,
                              hipStream_t stream) {
  (void)in_sizes; (void)n_in; (void)d_ws; (void)ws_size;
  const int blocks = out_size >> 1;  // 2 samples per block
  hqc_kernel<<<blocks, TPB, 0, stream>>>(
      (const float*)d_in[0],  (const float*)d_in[1],  (const float*)d_in[2],
      (const float*)d_in[3],  (const float*)d_in[4],  (const float*)d_in[5],
      (const float*)d_in[6],  (const float*)d_in[7],  (const float*)d_in[8],
      (const float*)d_in[9],  (const float*)d_in[10], (const float*)d_in[11],
      (const float*)d_in[12], (const float*)d_in[13],
      (float*)d_out);
}

// Round 4
// 96.836 us; speedup vs baseline: 1.3298x; 1.3298x over previous
//
#include <hip/hip_runtime.h>
#include <stdint.h>

#define NQ   12
#define DIM  4096   // 2^12 amplitudes
#define TPB  256

typedef float v2f __attribute__((ext_vector_type(2)));
typedef float v4f __attribute__((ext_vector_type(4)));
typedef _Float16 v2h __attribute__((ext_vector_type(2)));

// ---------- compile-time GF(2) circuit structure ----------
struct PassP {
  uint16_t v[4];     // pair XOR-vectors (columns of A^-k)
  uint16_t m[4];     // role parity masks (rows of A^k)
  uint16_t cmb[16];  // cmb[n] = XOR of v[i] over set bits of n
  uint8_t  np[8];    // free-bit positions (thread-bit k -> index bit np[k])
  uint8_t  layer;    // qparams layer (1 or 2)
  uint8_t  wbase;    // first wire of this group of 4
};
struct KP {
  PassP    pass[6];
  uint16_t ro_mask[12]; // rows of A^3 (readout parity masks)
  uint8_t  ro_bin[12];  // WHT bin per qubit over pass-5 coset directions
};

constexpr int chbit(uint32_t x) { int b = -1; for (int i = 0; i < 32; ++i) if ((x >> i) & 1u) b = i; return b; }

constexpr void bmm(uint32_t* C, const uint32_t* A, const uint32_t* B) {
  for (int i = 0; i < NQ; ++i) {
    uint32_t r = 0;
    for (int j = 0; j < NQ; ++j) if ((A[i] >> j) & 1u) r ^= B[j];
    C[i] = r;
  }
}
constexpr void binv(const uint32_t* M, uint32_t* Inv) {
  uint32_t A[NQ] = {}, I[NQ] = {};
  for (int i = 0; i < NQ; ++i) { A[i] = M[i]; I[i] = 1u << i; }
  for (int c = 0; c < NQ; ++c) {
    int piv = -1;
    for (int r = c; r < NQ; ++r) if ((A[r] >> c) & 1u) { piv = r; break; }
    if (piv < 0) continue;
    uint32_t ta = A[c]; A[c] = A[piv]; A[piv] = ta;
    uint32_t ti = I[c]; I[c] = I[piv]; I[piv] = ti;
    for (int r = 0; r < NQ; ++r)
      if (r != c && ((A[r] >> c) & 1u)) { A[r] ^= A[c]; I[r] ^= I[c]; }
  }
  for (int i = 0; i < NQ; ++i) Inv[i] = I[i];
}

constexpr KP make_kp() {
  KP kp{};
  // CNOT chain: q[i+1]^=q[i] for i=0..10, then q[0]^=q[11]
  uint32_t A[NQ] = {};
  A[0] = 0xFFEu;
  for (int i = 1; i < NQ; ++i) A[i] = (1u << (i + 1)) - 1u;
  uint32_t A2[NQ] = {}, A3[NQ] = {}, Ai[NQ] = {}, A2i[NQ] = {};
  bmm(A2, A, A); bmm(A3, A2, A);
  binv(A, Ai); binv(A2, A2i);

  for (int p = 0; p < 6; ++p) {
    int L = (p < 3) ? 1 : 2;
    int wb = (p % 3) * 4;
    const uint32_t* M  = (L == 1) ? A  : A2;
    const uint32_t* Mi = (L == 1) ? Ai : A2i;
    uint32_t v[4] = {}, m[4] = {};
    for (int i = 0; i < 4; ++i) {
      int w = wb + i;
      uint32_t col = 0;
      for (int r = 0; r < NQ; ++r) col |= ((Mi[r] >> w) & 1u) << r;
      v[i] = col; m[i] = M[w];
    }
    // pivot bits of span{v} -> 8 free (non-pivot) bit positions
    uint32_t redv[4] = {}; int pbit[4] = {}; uint32_t pivmask = 0;
    for (int i = 0; i < 4; ++i) {
      redv[i] = v[i];
      for (int k = 0; k < i; ++k) if ((redv[i] >> pbit[k]) & 1u) redv[i] ^= redv[k];
      pbit[i] = chbit(redv[i]);
      pivmask |= 1u << pbit[i];
    }
    uint8_t np0[8] = {};
    int c = 0;
    for (int b = 0; b < NQ; ++b)
      if (!((pivmask >> b) & 1u)) np0[c++] = (uint8_t)b;

    // bank-conflict-aware ordering for b32 LDS ops (32 banks):
    // base = B*rep, B = I ^ sum v_i m_i^T. Need lanes 0..31 to hit 32 distinct
    // (addr&31): low-5 rows of B restricted to {np[0..4]} must be rank-5.
    uint32_t Brow[5] = {};
    for (int r = 0; r < 5; ++r) {
      uint32_t row = 1u << r;
      for (int i = 0; i < 4; ++i) if ((v[i] >> r) & 1u) row ^= m[i];
      Brow[r] = row;
    }
    uint32_t colsig[8] = {};
    for (int cc = 0; cc < 8; ++cc) {
      uint32_t s = 0;
      for (int r = 0; r < 5; ++r) s |= ((Brow[r] >> np0[cc]) & 1u) << r;
      colsig[cc] = s;
    }
    int sel[5] = {0, 1, 2, 3, 4}; int bestrank = -1;
    bool found = false;
    for (int a = 0; a < 8 && !found; ++a)
      for (int b = a + 1; b < 8 && !found; ++b)
        for (int cx = b + 1; cx < 8 && !found; ++cx)
          for (int d = cx + 1; d < 8 && !found; ++d)
            for (int e = d + 1; e < 8 && !found; ++e) {
              uint32_t rows2[5] = {}; int rnk = 0;
              int idxs[5] = {a, b, cx, d, e};
              for (int q = 0; q < 5; ++q) {
                uint32_t xx = colsig[idxs[q]];
                for (int bit = 4; bit >= 0; --bit) {
                  if (!((xx >> bit) & 1u)) continue;
                  if (rows2[bit]) { xx ^= rows2[bit]; }
                  else { rows2[bit] = xx; ++rnk; break; }
                }
              }
              if (rnk > bestrank) {
                bestrank = rnk;
                sel[0] = a; sel[1] = b; sel[2] = cx; sel[3] = d; sel[4] = e;
                if (rnk == 5) found = true;
              }
            }
    uint8_t npn[8] = {};
    for (int q = 0; q < 5; ++q) npn[q] = np0[sel[q]];
    int cn = 5;
    for (int cc = 0; cc < 8; ++cc) {
      bool used = false;
      for (int q = 0; q < 5; ++q) if (sel[q] == cc) used = true;
      if (!used) npn[cn++] = np0[cc];
    }
    for (int cc = 0; cc < 8; ++cc) kp.pass[p].np[cc] = npn[cc];

    for (int n = 0; n < 16; ++n) {
      uint32_t cm = 0;
      for (int i = 0; i < 4; ++i) if ((n >> i) & 1) cm ^= v[i];
      kp.pass[p].cmb[n] = (uint16_t)cm;
    }
    for (int i = 0; i < 4; ++i) { kp.pass[p].v[i] = (uint16_t)v[i]; kp.pass[p].m[i] = (uint16_t)m[i]; }
    kp.pass[p].layer = (uint8_t)L; kp.pass[p].wbase = (uint8_t)wb;
  }
  for (int i = 0; i < NQ; ++i) kp.ro_mask[i] = (uint16_t)A3[i];
  for (int i = 0; i < NQ; ++i) {
    uint32_t b = 0;
    for (int j = 0; j < 4; ++j)
      b |= (uint32_t)(__builtin_popcount(A3[i] & (uint32_t)kp.pass[5].v[j]) & 1) << j;
    kp.ro_bin[i] = (uint8_t)b;
  }
  return kp;
}

constexpr KP kpc = make_kp();

// ---------- device helpers ----------
__device__ __forceinline__ v2f h2f(uint32_t u) {
  v2h h = __builtin_bit_cast(v2h, u);
  return (v2f){(float)h.x, (float)h.y};
}
__device__ __forceinline__ uint32_t f2h(v2f a) {
  return __builtin_bit_cast(uint32_t, __builtin_amdgcn_cvt_pkrtz(a.x, a.y));
}

__device__ __forceinline__ void build_u(const float* __restrict__ qp, int l, int w, float U[8]) {
  float p0 = qp[(l * 12 + w) * 3 + 0];
  float p1 = qp[(l * 12 + w) * 3 + 1];
  float p2 = qp[(l * 12 + w) * 3 + 2];
  float cx, sx, cy, sy, cz, sz;
  sincosf(0.5f * p0, &sx, &cx);
  sincosf(0.5f * p1, &sy, &cy);
  sincosf(0.5f * p2, &sz, &cz);
  float M00x =  cy * cx, M00y =  sy * sx;
  float M01x = -sy * cx, M01y = -cy * sx;
  float M10x =  sy * cx, M10y = -cy * sx;
  float M11x =  cy * cx, M11y = -sy * sx;
  U[0] = cz * M00x + sz * M00y; U[1] = cz * M00y - sz * M00x;
  U[2] = cz * M01x + sz * M01y; U[3] = cz * M01y - sz * M01x;
  U[4] = cz * M10x - sz * M10y; U[5] = cz * M10y + sz * M10x;
  U[6] = cz * M11x - sz * M11y; U[7] = cz * M11y + sz * M11x;
}

template<int P>
__device__ __forceinline__ int pass_base(int t) {
  int rep = 0;
  #pragma unroll
  for (int k = 0; k < 8; ++k) rep |= ((t >> k) & 1) << kpc.pass[P].np[k];
  int rho = 0;
  #pragma unroll
  for (int i = 0; i < 4; ++i) rho |= (__popc(kpc.pass[P].m[i] & rep) & 1) << i;
  int base = rep;
  #pragma unroll
  for (int i = 0; i < 4; ++i) if ((rho >> i) & 1) base ^= kpc.pass[P].v[i];
  return base;
}

template<int P>
__device__ __forceinline__ void pass_chew(const v4f (*gp)[4], v2f sl[16]) {
  constexpr int wb = kpc.pass[P].wbase;
  #pragma unroll
  for (int i = 0; i < 4; ++i) {
    v4f gA = gp[wb + i][0], gB = gp[wb + i][1];
    v4f gC = gp[wb + i][2], gD = gp[wb + i][3];
    #pragma unroll
    for (int r = 0; r < 16; ++r) {
      if (r & (1 << i)) continue;
      int r1 = r | (1 << i);
      v2f a0 = sl[r], a1 = sl[r1];
      v2f a0s = a0.yx, a1s = a1.yx;
      sl[r]  = gA.xy * a0 + gA.zw * a0s + gB.xy * a1 + gB.zw * a1s;
      sl[r1] = gC.xy * a0 + gC.zw * a0s + gD.xy * a1 + gD.zw * a1s;
    }
  }
}

__device__ __forceinline__ void readout_ev(const v2f sl[16], int base, float ev[NQ]) {
  float pr[16];
  #pragma unroll
  for (int r = 0; r < 16; ++r) pr[r] = sl[r].x * sl[r].x + sl[r].y * sl[r].y;
  #pragma unroll
  for (int g = 1; g < 16; g <<= 1) {
    #pragma unroll
    for (int j = 0; j < 16; ++j) {
      if (j & g) continue;
      float u = pr[j], w2 = pr[j | g];
      pr[j] = u + w2; pr[j | g] = u - w2;
    }
  }
  #pragma unroll
  for (int i = 0; i < NQ; ++i) {
    float h = pr[kpc.ro_bin[i]];
    int sgn = (__popc((int)kpc.ro_mask[i] & base) & 1) << 31;
    ev[i] = __int_as_float(__float_as_int(h) ^ sgn);
  }
}

// ---------- kernel: 1 sample per block, f16-packed statevector ----------
__global__ __launch_bounds__(TPB, 8) void hqc_kernel(
    const float* __restrict__ x,  const float* __restrict__ W1, const float* __restrict__ b1,
    const float* __restrict__ W2, const float* __restrict__ b2,
    const float* __restrict__ W3, const float* __restrict__ b3,
    const float* __restrict__ qp, const float* __restrict__ P1, const float* __restrict__ c1,
    const float* __restrict__ P2, const float* __restrict__ c2,
    const float* __restrict__ P3, const float* __restrict__ c3,
    float* __restrict__ out)
{
  __shared__ uint32_t st[DIM];         // 16 KB: statevector as packed half2
  __shared__ v4f  gpk[3][NQ][4];       // gates packed {x,x,-y,y}
  __shared__ float red[4][NQ];         // per-wave readout partials

  const int s    = blockIdx.x;
  const int t    = threadIdx.x;
  const int lane = t & 63;
  const int wv   = t >> 6;

  // ---- phase 0 (one barrier): wave0 = MLP + L0-folded gates; wave1/2 = L1/L2 ----
  if (wv == 0) {
    if (lane < 16) {
      float a = b1[lane];
      #pragma unroll
      for (int k = 0; k < 6; ++k) a = fmaf(W1[lane * 6 + k], x[s * 6 + k], a);
      float h1 = fmaxf(a, 0.f);
      float a2 = b2[lane];
      #pragma unroll
      for (int k = 0; k < 16; ++k) a2 = fmaf(W2[lane * 16 + k], __shfl(h1, k, 64), a2);
      float h2 = fmaxf(a2, 0.f);
      const int lw = (lane < NQ) ? lane : 0;
      float a3 = b3[lw];
      #pragma unroll
      for (int k = 0; k < 16; ++k) a3 = fmaf(W3[lw * 16 + k], __shfl(h2, k, 64), a3);
      if (lane < NQ) {
        float U[8]; build_u(qp, 0, lane, U);
        float ca, sa; sincosf(0.5f * a3, &sa, &ca);
        float c0x = U[0] * ca + U[2] * sa, c0y = U[1] * ca + U[3] * sa;
        float c1x = U[4] * ca + U[6] * sa, c1y = U[5] * ca + U[7] * sa;
        gpk[0][lane][0] = (v4f){c0x, c0x, -c0y, c0y};
        gpk[0][lane][1] = (v4f){c1x, c1x, -c1y, c1y};
      }
    }
  } else if (wv <= 2) {
    if (lane < NQ) {
      float U[8]; build_u(qp, wv, lane, U);
      gpk[wv][lane][0] = (v4f){U[0], U[0], -U[1], U[1]};
      gpk[wv][lane][1] = (v4f){U[2], U[2], -U[3], U[3]};
      gpk[wv][lane][2] = (v4f){U[4], U[4], -U[5], U[5]};
      gpk[wv][lane][3] = (v4f){U[6], U[6], -U[7], U[7]};
    }
  }
  __syncthreads();

  // ---- product-state init: idx = t | (j<<8) ----
  {
    v2f acc = (v2f){1.f, 0.f};
    #pragma unroll
    for (int i = 0; i < 8; ++i) {
      v4f g = gpk[0][i][(t >> i) & 1];
      acc = g.xy * acc + g.zw * acc.yx;
    }
    v2f l16[16];
    l16[0] = acc;
    #pragma unroll
    for (int i = 0; i < 4; ++i) {
      v4f g0 = gpk[0][8 + i][0], g1 = gpk[0][8 + i][1];
      #pragma unroll
      for (int j = 0; j < (1 << i); ++j) {
        v2f a = l16[j];
        l16[j | (1 << i)] = g1.xy * a + g1.zw * a.yx;
        l16[j]            = g0.xy * a + g0.zw * a.yx;
      }
    }
    #pragma unroll
    for (int j = 0; j < 16; ++j) st[t | (j << 8)] = f2h(l16[j]);
  }
  __syncthreads();

  // ---- passes 0..4 ----
  #define DO_PASS(P)                                            \
  {                                                             \
    constexpr int L = kpc.pass[P].layer;                        \
    const int base = pass_base<P>(t);                           \
    v2f sl[16];                                                 \
    _Pragma("unroll")                                           \
    for (int r = 0; r < 16; ++r) sl[r] = h2f(st[base ^ kpc.pass[P].cmb[r]]); \
    pass_chew<P>(gpk[L], sl);                                   \
    _Pragma("unroll")                                           \
    for (int r = 0; r < 16; ++r) st[base ^ kpc.pass[P].cmb[r]] = f2h(sl[r]); \
    __syncthreads();                                            \
  }
  DO_PASS(0)
  DO_PASS(1)
  DO_PASS(2)
  DO_PASS(3)
  DO_PASS(4)
  #undef DO_PASS

  // ---- pass 5 with fused readout (no final store/reload) ----
  {
    const int base = pass_base<5>(t);
    v2f sl[16];
    #pragma unroll
    for (int r = 0; r < 16; ++r) sl[r] = h2f(st[base ^ kpc.pass[5].cmb[r]]);
    pass_chew<5>(gpk[2], sl);
    float ev[NQ];
    readout_ev(sl, base, ev);
    #pragma unroll
    for (int off = 32; off >= 1; off >>= 1) {
      #pragma unroll
      for (int i = 0; i < NQ; ++i) ev[i] += __shfl_xor(ev[i], off, 64);
    }
    if (lane == 0) {
      #pragma unroll
      for (int i = 0; i < NQ; ++i) red[wv][i] = ev[i];
    }
  }
  __syncthreads();

  // ---- post-MLP on wave 0 via shuffles ----
  if (wv == 0 && lane < 16) {
    float q = (lane < NQ)
      ? (red[0][lane] + red[1][lane] + red[2][lane] + red[3][lane])
      : 0.f;
    float a = c1[lane];
    #pragma unroll
    for (int j = 0; j < NQ; ++j) a = fmaf(P1[lane * NQ + j], __shfl(q, j, 64), a);
    float o1 = fmaxf(a, 0.f);
    float a2 = c2[lane & 7];
    #pragma unroll
    for (int j = 0; j < 16; ++j) a2 = fmaf(P2[(lane & 7) * 16 + j], __shfl(o1, j, 64), a2);
    float o2 = fmaxf(a2, 0.f);
    float a3 = c3[0];
    #pragma unroll
    for (int j = 0; j < 8; ++j) a3 = fmaf(P3[j], __shfl(o2, j, 64), a3);
    if (lane == 0) out[s] = 1.f / (1.f + expf(-a3));
  }
}

extern "C" void kernel_launch(void* const* d_in, const int* in_sizes, int n_in,
                              void* d_out, int out_size, void* d_ws, size_t ws_size,
                              hipStream_t stream) {
  (void)in_sizes; (void)n_in; (void)d_ws; (void)ws_size;
  hqc_kernel<<<out_size, TPB, 0, stream>>>(
      (const float*)d_in[0],  (const float*)d_in[1],  (const float*)d_in[2],
      (const float*)d_in[3],  (const float*)d_in[4],  (const float*)d_in[5],
      (const float*)d_in[6],  (const float*)d_in[7],  (const float*)d_in[8],
      (const float*)d_in[9],  (const float*)d_in[10], (const float*)d_in[11],
      (const float*)d_in[12], (const float*)d_in[13],
      (float*)d_out);
}

// Round 5
// 93.737 us; speedup vs baseline: 1.3738x; 1.0331x over previous
//
#include <hip/hip_runtime.h>
#include <stdint.h>

#define NQ   12
#define DIM  4096   // 2^12 amplitudes
#define TPB  256

typedef float v2f __attribute__((ext_vector_type(2)));
typedef float v4f __attribute__((ext_vector_type(4)));
typedef _Float16 v2h __attribute__((ext_vector_type(2)));

// ---------- compile-time GF(2) circuit structure ----------
struct PassP {
  uint16_t v[4];     // pair XOR-vectors (columns of A^-k)
  uint16_t m[4];     // role parity masks (rows of A^k)
  uint16_t cmb[16];  // cmb[n] = XOR of v[i] over set bits of n
  uint8_t  np[8];    // free-bit positions (thread-bit k -> index bit np[k])
  uint8_t  layer;    // qparams layer (1 or 2)
  uint8_t  wbase;    // first wire of this group of 4
};
struct KP {
  PassP    pass[6];
  uint16_t ro_mask[12]; // rows of A^3 (readout parity masks)
  uint8_t  ro_bin[12];  // WHT bin per qubit over pass-5 coset directions
};

constexpr int chbit(uint32_t x) { int b = -1; for (int i = 0; i < 32; ++i) if ((x >> i) & 1u) b = i; return b; }

constexpr void bmm(uint32_t* C, const uint32_t* A, const uint32_t* B) {
  for (int i = 0; i < NQ; ++i) {
    uint32_t r = 0;
    for (int j = 0; j < NQ; ++j) if ((A[i] >> j) & 1u) r ^= B[j];
    C[i] = r;
  }
}
constexpr void binv(const uint32_t* M, uint32_t* Inv) {
  uint32_t A[NQ] = {}, I[NQ] = {};
  for (int i = 0; i < NQ; ++i) { A[i] = M[i]; I[i] = 1u << i; }
  for (int c = 0; c < NQ; ++c) {
    int piv = -1;
    for (int r = c; r < NQ; ++r) if ((A[r] >> c) & 1u) { piv = r; break; }
    if (piv < 0) continue;
    uint32_t ta = A[c]; A[c] = A[piv]; A[piv] = ta;
    uint32_t ti = I[c]; I[c] = I[piv]; I[piv] = ti;
    for (int r = 0; r < NQ; ++r)
      if (r != c && ((A[r] >> c) & 1u)) { A[r] ^= A[c]; I[r] ^= I[c]; }
  }
  for (int i = 0; i < NQ; ++i) Inv[i] = I[i];
}

constexpr KP make_kp() {
  KP kp{};
  // CNOT chain: q[i+1]^=q[i] for i=0..10, then q[0]^=q[11]
  uint32_t A[NQ] = {};
  A[0] = 0xFFEu;
  for (int i = 1; i < NQ; ++i) A[i] = (1u << (i + 1)) - 1u;
  uint32_t A2[NQ] = {}, A3[NQ] = {}, Ai[NQ] = {}, A2i[NQ] = {};
  bmm(A2, A, A); bmm(A3, A2, A);
  binv(A, Ai); binv(A2, A2i);

  for (int p = 0; p < 6; ++p) {
    int L = (p < 3) ? 1 : 2;
    int wb = (p % 3) * 4;
    const uint32_t* M  = (L == 1) ? A  : A2;
    const uint32_t* Mi = (L == 1) ? Ai : A2i;
    uint32_t v[4] = {}, m[4] = {};
    for (int i = 0; i < 4; ++i) {
      int w = wb + i;
      uint32_t col = 0;
      for (int r = 0; r < NQ; ++r) col |= ((Mi[r] >> w) & 1u) << r;
      v[i] = col; m[i] = M[w];
    }
    // pivot bits of span{v} -> 8 free (non-pivot) bit positions
    uint32_t redv[4] = {}; int pbit[4] = {}; uint32_t pivmask = 0;
    for (int i = 0; i < 4; ++i) {
      redv[i] = v[i];
      for (int k = 0; k < i; ++k) if ((redv[i] >> pbit[k]) & 1u) redv[i] ^= redv[k];
      pbit[i] = chbit(redv[i]);
      pivmask |= 1u << pbit[i];
    }
    uint8_t np0[8] = {};
    int c = 0;
    for (int b = 0; b < NQ; ++b)
      if (!((pivmask >> b) & 1u)) np0[c++] = (uint8_t)b;

    // bank-conflict-aware ordering for b32 LDS ops (32 banks):
    // base = B*rep, B = I ^ sum v_i m_i^T. Need lanes 0..31 to hit 32 distinct
    // (addr&31): low-5 rows of B restricted to {np[0..4]} must be rank-5.
    uint32_t Brow[5] = {};
    for (int r = 0; r < 5; ++r) {
      uint32_t row = 1u << r;
      for (int i = 0; i < 4; ++i) if ((v[i] >> r) & 1u) row ^= m[i];
      Brow[r] = row;
    }
    uint32_t colsig[8] = {};
    for (int cc = 0; cc < 8; ++cc) {
      uint32_t s = 0;
      for (int r = 0; r < 5; ++r) s |= ((Brow[r] >> np0[cc]) & 1u) << r;
      colsig[cc] = s;
    }
    int sel[5] = {0, 1, 2, 3, 4}; int bestrank = -1;
    bool found = false;
    for (int a = 0; a < 8 && !found; ++a)
      for (int b = a + 1; b < 8 && !found; ++b)
        for (int cx = b + 1; cx < 8 && !found; ++cx)
          for (int d = cx + 1; d < 8 && !found; ++d)
            for (int e = d + 1; e < 8 && !found; ++e) {
              uint32_t rows2[5] = {}; int rnk = 0;
              int idxs[5] = {a, b, cx, d, e};
              for (int q = 0; q < 5; ++q) {
                uint32_t xx = colsig[idxs[q]];
                for (int bit = 4; bit >= 0; --bit) {
                  if (!((xx >> bit) & 1u)) continue;
                  if (rows2[bit]) { xx ^= rows2[bit]; }
                  else { rows2[bit] = xx; ++rnk; break; }
                }
              }
              if (rnk > bestrank) {
                bestrank = rnk;
                sel[0] = a; sel[1] = b; sel[2] = cx; sel[3] = d; sel[4] = e;
                if (rnk == 5) found = true;
              }
            }
    uint8_t npn[8] = {};
    for (int q = 0; q < 5; ++q) npn[q] = np0[sel[q]];
    int cn = 5;
    for (int cc = 0; cc < 8; ++cc) {
      bool used = false;
      for (int q = 0; q < 5; ++q) if (sel[q] == cc) used = true;
      if (!used) npn[cn++] = np0[cc];
    }
    for (int cc = 0; cc < 8; ++cc) kp.pass[p].np[cc] = npn[cc];

    for (int n = 0; n < 16; ++n) {
      uint32_t cm = 0;
      for (int i = 0; i < 4; ++i) if ((n >> i) & 1) cm ^= v[i];
      kp.pass[p].cmb[n] = (uint16_t)cm;
    }
    for (int i = 0; i < 4; ++i) { kp.pass[p].v[i] = (uint16_t)v[i]; kp.pass[p].m[i] = (uint16_t)m[i]; }
    kp.pass[p].layer = (uint8_t)L; kp.pass[p].wbase = (uint8_t)wb;
  }
  for (int i = 0; i < NQ; ++i) kp.ro_mask[i] = (uint16_t)A3[i];
  for (int i = 0; i < NQ; ++i) {
    uint32_t b = 0;
    for (int j = 0; j < 4; ++j)
      b |= (uint32_t)(__builtin_popcount(A3[i] & (uint32_t)kp.pass[5].v[j]) & 1) << j;
    kp.ro_bin[i] = (uint8_t)b;
  }
  return kp;
}

constexpr KP kpc = make_kp();

// ---------- device helpers ----------
__device__ __forceinline__ v2f h2f(uint32_t u) {
  v2h h = __builtin_bit_cast(v2h, u);
  return (v2f){(float)h.x, (float)h.y};
}
__device__ __forceinline__ uint32_t f2h(v2f a) {
  return __builtin_bit_cast(uint32_t, __builtin_amdgcn_cvt_pkrtz(a.x, a.y));
}

__device__ __forceinline__ void build_u(const float* __restrict__ qp, int l, int w, float U[8]) {
  float p0 = qp[(l * 12 + w) * 3 + 0];
  float p1 = qp[(l * 12 + w) * 3 + 1];
  float p2 = qp[(l * 12 + w) * 3 + 2];
  float cx, sx, cy, sy, cz, sz;
  sincosf(0.5f * p0, &sx, &cx);
  sincosf(0.5f * p1, &sy, &cy);
  sincosf(0.5f * p2, &sz, &cz);
  float M00x =  cy * cx, M00y =  sy * sx;
  float M01x = -sy * cx, M01y = -cy * sx;
  float M10x =  sy * cx, M10y = -cy * sx;
  float M11x =  cy * cx, M11y = -sy * sx;
  U[0] = cz * M00x + sz * M00y; U[1] = cz * M00y - sz * M00x;
  U[2] = cz * M01x + sz * M01y; U[3] = cz * M01y - sz * M01x;
  U[4] = cz * M10x - sz * M10y; U[5] = cz * M10y + sz * M10x;
  U[6] = cz * M11x - sz * M11y; U[7] = cz * M11y + sz * M11x;
}

template<int P>
__device__ __forceinline__ int pass_base(int t) {
  int rep = 0;
  #pragma unroll
  for (int k = 0; k < 8; ++k) rep |= ((t >> k) & 1) << kpc.pass[P].np[k];
  int rho = 0;
  #pragma unroll
  for (int i = 0; i < 4; ++i) rho |= (__popc(kpc.pass[P].m[i] & rep) & 1) << i;
  int base = rep;
  #pragma unroll
  for (int i = 0; i < 4; ++i) if ((rho >> i) & 1) base ^= kpc.pass[P].v[i];
  return base;
}

template<int P>
__device__ __forceinline__ void pass_chew(const v4f (*gp)[4], v2f sl[16]) {
  constexpr int wb = kpc.pass[P].wbase;
  #pragma unroll
  for (int i = 0; i < 4; ++i) {
    v4f gA = gp[wb + i][0], gB = gp[wb + i][1];
    v4f gC = gp[wb + i][2], gD = gp[wb + i][3];
    #pragma unroll
    for (int r = 0; r < 16; ++r) {
      if (r & (1 << i)) continue;
      int r1 = r | (1 << i);
      v2f a0 = sl[r], a1 = sl[r1];
      v2f a0s = a0.yx, a1s = a1.yx;
      sl[r]  = gA.xy * a0 + gA.zw * a0s + gB.xy * a1 + gB.zw * a1s;
      sl[r1] = gC.xy * a0 + gC.zw * a0s + gD.xy * a1 + gD.zw * a1s;
    }
  }
}

__device__ __forceinline__ void readout_ev(const v2f sl[16], int base, float ev[NQ]) {
  float pr[16];
  #pragma unroll
  for (int r = 0; r < 16; ++r) pr[r] = sl[r].x * sl[r].x + sl[r].y * sl[r].y;
  #pragma unroll
  for (int g = 1; g < 16; g <<= 1) {
    #pragma unroll
    for (int j = 0; j < 16; ++j) {
      if (j & g) continue;
      float u = pr[j], w2 = pr[j | g];
      pr[j] = u + w2; pr[j | g] = u - w2;
    }
  }
  #pragma unroll
  for (int i = 0; i < NQ; ++i) {
    float h = pr[kpc.ro_bin[i]];
    int sgn = (__popc((int)kpc.ro_mask[i] & base) & 1) << 31;
    ev[i] = __int_as_float(__float_as_int(h) ^ sgn);
  }
}

// ---------- kernel: 1 sample per block, f16-packed statevector ----------
// launch_bounds(256, 6): 6 waves/EU -> VGPR cap ~85, fits the ~70-reg working
// set with NO scratch spill (round 4's (256,8) capped at 32 VGPR -> 88 MB of
// spill traffic per dispatch). 24 waves/CU vs 32: small TLP loss, big win.
__global__ __launch_bounds__(TPB, 6) void hqc_kernel(
    const float* __restrict__ x,  const float* __restrict__ W1, const float* __restrict__ b1,
    const float* __restrict__ W2, const float* __restrict__ b2,
    const float* __restrict__ W3, const float* __restrict__ b3,
    const float* __restrict__ qp, const float* __restrict__ P1, const float* __restrict__ c1,
    const float* __restrict__ P2, const float* __restrict__ c2,
    const float* __restrict__ P3, const float* __restrict__ c3,
    float* __restrict__ out)
{
  __shared__ uint32_t st[DIM];         // 16 KB: statevector as packed half2
  __shared__ v4f  gpk[3][NQ][4];       // gates packed {x,x,-y,y}
  __shared__ float red[4][NQ];         // per-wave readout partials

  const int s    = blockIdx.x;
  const int t    = threadIdx.x;
  const int lane = t & 63;
  const int wv   = t >> 6;

  // ---- phase 0 (one barrier): wave0 = MLP + L0-folded gates; wave1/2 = L1/L2 ----
  if (wv == 0) {
    if (lane < 16) {
      float a = b1[lane];
      #pragma unroll
      for (int k = 0; k < 6; ++k) a = fmaf(W1[lane * 6 + k], x[s * 6 + k], a);
      float h1 = fmaxf(a, 0.f);
      float a2 = b2[lane];
      #pragma unroll
      for (int k = 0; k < 16; ++k) a2 = fmaf(W2[lane * 16 + k], __shfl(h1, k, 64), a2);
      float h2 = fmaxf(a2, 0.f);
      const int lw = (lane < NQ) ? lane : 0;
      float a3 = b3[lw];
      #pragma unroll
      for (int k = 0; k < 16; ++k) a3 = fmaf(W3[lw * 16 + k], __shfl(h2, k, 64), a3);
      if (lane < NQ) {
        float U[8]; build_u(qp, 0, lane, U);
        float ca, sa; sincosf(0.5f * a3, &sa, &ca);
        float c0x = U[0] * ca + U[2] * sa, c0y = U[1] * ca + U[3] * sa;
        float c1x = U[4] * ca + U[6] * sa, c1y = U[5] * ca + U[7] * sa;
        gpk[0][lane][0] = (v4f){c0x, c0x, -c0y, c0y};
        gpk[0][lane][1] = (v4f){c1x, c1x, -c1y, c1y};
      }
    }
  } else if (wv <= 2) {
    if (lane < NQ) {
      float U[8]; build_u(qp, wv, lane, U);
      gpk[wv][lane][0] = (v4f){U[0], U[0], -U[1], U[1]};
      gpk[wv][lane][1] = (v4f){U[2], U[2], -U[3], U[3]};
      gpk[wv][lane][2] = (v4f){U[4], U[4], -U[5], U[5]};
      gpk[wv][lane][3] = (v4f){U[6], U[6], -U[7], U[7]};
    }
  }
  __syncthreads();

  // ---- product-state init: idx = t | (j<<8) ----
  {
    v2f acc = (v2f){1.f, 0.f};
    #pragma unroll
    for (int i = 0; i < 8; ++i) {
      v4f g = gpk[0][i][(t >> i) & 1];
      acc = g.xy * acc + g.zw * acc.yx;
    }
    v2f l16[16];
    l16[0] = acc;
    #pragma unroll
    for (int i = 0; i < 4; ++i) {
      v4f g0 = gpk[0][8 + i][0], g1 = gpk[0][8 + i][1];
      #pragma unroll
      for (int j = 0; j < (1 << i); ++j) {
        v2f a = l16[j];
        l16[j | (1 << i)] = g1.xy * a + g1.zw * a.yx;
        l16[j]            = g0.xy * a + g0.zw * a.yx;
      }
    }
    #pragma unroll
    for (int j = 0; j < 16; ++j) st[t | (j << 8)] = f2h(l16[j]);
  }
  __syncthreads();

  // ---- passes 0..4 ----
  #define DO_PASS(P)                                            \
  {                                                             \
    constexpr int L = kpc.pass[P].layer;                        \
    const int base = pass_base<P>(t);                           \
    v2f sl[16];                                                 \
    _Pragma("unroll")                                           \
    for (int r = 0; r < 16; ++r) sl[r] = h2f(st[base ^ kpc.pass[P].cmb[r]]); \
    pass_chew<P>(gpk[L], sl);                                   \
    _Pragma("unroll")                                           \
    for (int r = 0; r < 16; ++r) st[base ^ kpc.pass[P].cmb[r]] = f2h(sl[r]); \
    __syncthreads();                                            \
  }
  DO_PASS(0)
  DO_PASS(1)
  DO_PASS(2)
  DO_PASS(3)
  DO_PASS(4)
  #undef DO_PASS

  // ---- pass 5 with fused readout (no final store/reload) ----
  {
    const int base = pass_base<5>(t);
    v2f sl[16];
    #pragma unroll
    for (int r = 0; r < 16; ++r) sl[r] = h2f(st[base ^ kpc.pass[5].cmb[r]]);
    pass_chew<5>(gpk[2], sl);
    float ev[NQ];
    readout_ev(sl, base, ev);
    #pragma unroll
    for (int off = 32; off >= 1; off >>= 1) {
      #pragma unroll
      for (int i = 0; i < NQ; ++i) ev[i] += __shfl_xor(ev[i], off, 64);
    }
    if (lane == 0) {
      #pragma unroll
      for (int i = 0; i < NQ; ++i) red[wv][i] = ev[i];
    }
  }
  __syncthreads();

  // ---- post-MLP on wave 0 via shuffles ----
  if (wv == 0 && lane < 16) {
    float q = (lane < NQ)
      ? (red[0][lane] + red[1][lane] + red[2][lane] + red[3][lane])
      : 0.f;
    float a = c1[lane];
    #pragma unroll
    for (int j = 0; j < NQ; ++j) a = fmaf(P1[lane * NQ + j], __shfl(q, j, 64), a);
    float o1 = fmaxf(a, 0.f);
    float a2 = c2[lane & 7];
    #pragma unroll
    for (int j = 0; j < 16; ++j) a2 = fmaf(P2[(lane & 7) * 16 + j], __shfl(o1, j, 64), a2);
    float o2 = fmaxf(a2, 0.f);
    float a3 = c3[0];
    #pragma unroll
    for (int j = 0; j < 8; ++j) a3 = fmaf(P3[j], __shfl(o2, j, 64), a3);
    if (lane == 0) out[s] = 1.f / (1.f + expf(-a3));
  }
}

extern "C" void kernel_launch(void* const* d_in, const int* in_sizes, int n_in,
                              void* d_out, int out_size, void* d_ws, size_t ws_size,
                              hipStream_t stream) {
  (void)in_sizes; (void)n_in; (void)d_ws; (void)ws_size;
  hqc_kernel<<<out_size, TPB, 0, stream>>>(
      (const float*)d_in[0],  (const float*)d_in[1],  (const float*)d_in[2],
      (const float*)d_in[3],  (const float*)d_in[4],  (const float*)d_in[5],
      (const float*)d_in[6],  (const float*)d_in[7],  (const float*)d_in[8],
      (const float*)d_in[9],  (const float*)d_in[10], (const float*)d_in[11],
      (const float*)d_in[12], (const float*)d_in[13],
      (float*)d_out);
}

// Round 6
// 57.671 us; speedup vs baseline: 2.2329x; 1.6254x over previous
//
#include <hip/hip_runtime.h>
#include <stdint.h>

#define NQ   12
#define DIM  4096   // 2^12 amplitudes
#define TPB  256

typedef float   v2f   __attribute__((ext_vector_type(2)));
typedef float   v4f   __attribute__((ext_vector_type(4)));
typedef float   f32x4 __attribute__((ext_vector_type(4)));
typedef _Float16 v2h  __attribute__((ext_vector_type(2)));
typedef _Float16 f16x8 __attribute__((ext_vector_type(8)));
typedef uint32_t u32x4 __attribute__((ext_vector_type(4)));

// ---------- compile-time GF(2) circuit structure ----------
struct PassP {
  uint16_t v[4];    // pair XOR-vectors (permuted order: bit i of r <-> v[i])
  uint16_t m[4];    // role parity masks (permuted to match v)
  uint16_t td[4];   // baseT deltas (B * T-bit columns)
  uint8_t  np[8];   // free-bit slots: [0..3]=j, [4..5]=T, [6..7]=wave
  uint8_t  wire[4]; // absolute wire index for r-bit i
  uint8_t  layer;   // 1 or 2
  uint8_t  pad[3];
};
struct KP {
  PassP    pass[6];
  uint16_t ro_mask[12]; // rows of A^3
  uint8_t  ro_bin[12];  // WHT bin per qubit over pass5 lane-span {v0,v3,td1,td2}
};

constexpr int chbit(uint32_t x) { int b = -1; for (int i = 0; i < 32; ++i) if ((x >> i) & 1u) b = i; return b; }

constexpr void bmm(uint32_t* C, const uint32_t* A, const uint32_t* B) {
  for (int i = 0; i < NQ; ++i) {
    uint32_t r = 0;
    for (int j = 0; j < NQ; ++j) if ((A[i] >> j) & 1u) r ^= B[j];
    C[i] = r;
  }
}
constexpr void binv(const uint32_t* M, uint32_t* Inv) {
  uint32_t A[NQ] = {}, I[NQ] = {};
  for (int i = 0; i < NQ; ++i) { A[i] = M[i]; I[i] = 1u << i; }
  for (int c = 0; c < NQ; ++c) {
    int piv = -1;
    for (int r = c; r < NQ; ++r) if ((A[r] >> c) & 1u) { piv = r; break; }
    if (piv < 0) continue;
    uint32_t ta = A[c]; A[c] = A[piv]; A[piv] = ta;
    uint32_t ti = I[c]; I[c] = I[piv]; I[piv] = ti;
    for (int r = 0; r < NQ; ++r)
      if (r != c && ((A[r] >> c) & 1u)) { A[r] ^= A[c]; I[r] ^= I[c]; }
  }
  for (int i = 0; i < NQ; ++i) Inv[i] = I[i];
}

constexpr int rank5(const uint32_t* cols, int n) {
  uint32_t rows[5] = {}; int rnk = 0;
  for (int q = 0; q < n; ++q) {
    uint32_t x = cols[q] & 31u;
    for (int bit = 4; bit >= 0; --bit) {
      if (!((x >> bit) & 1u)) continue;
      if (rows[bit]) { x ^= rows[bit]; }
      else { rows[bit] = x; ++rnk; break; }
    }
  }
  return rnk;
}

constexpr KP make_kp() {
  KP kp{};
  uint32_t A[NQ] = {}; A[0] = 0xFFEu;
  for (int i = 1; i < NQ; ++i) A[i] = (1u << (i + 1)) - 1u;
  uint32_t A2[NQ] = {}, A3[NQ] = {}, Ai[NQ] = {}, A2i[NQ] = {};
  bmm(A2, A, A); bmm(A3, A2, A);
  binv(A, Ai); binv(A2, A2i);

  uint32_t v5_0 = 0, v5_3 = 0, td5_1 = 0, td5_2 = 0;

  for (int p = 0; p < 6; ++p) {
    const int L = (p < 3) ? 1 : 2;
    const int wb = (p % 3) * 4;
    const uint32_t* M  = (L == 1) ? A  : A2;
    const uint32_t* Mi = (L == 1) ? Ai : A2i;
    uint32_t v0[4] = {}, m0[4] = {};
    for (int i = 0; i < 4; ++i) {
      int w = wb + i; uint32_t col = 0;
      for (int r = 0; r < NQ; ++r) col |= ((Mi[r] >> w) & 1u) << r;
      v0[i] = col; m0[i] = M[w];
    }
    // B = I ^ sum v_i m_i^T (perm-invariant); columns:
    uint32_t Bc[NQ] = {};
    for (int b = 0; b < NQ; ++b) {
      uint32_t col = 1u << b;
      for (int i = 0; i < 4; ++i) if ((m0[i] >> b) & 1u) col ^= v0[i];
      Bc[b] = col;
    }
    // free (non-pivot) bits of span{v}
    uint32_t redv[4] = {}; int pbit[4] = {}; uint32_t pivmask = 0;
    for (int i = 0; i < 4; ++i) {
      redv[i] = v0[i];
      for (int k2 = 0; k2 < i; ++k2) if ((redv[i] >> pbit[k2]) & 1u) redv[i] ^= redv[k2];
      pbit[i] = chbit(redv[i]); pivmask |= 1u << pbit[i];
    }
    uint8_t np0[8] = {}; int nc = 0;
    for (int b = 0; b < NQ; ++b) if (!((pivmask >> b) & 1u)) np0[nc++] = (uint8_t)b;

    // search: j-slot selection (rank-4 banks), T slots, pair-vector permutation
    int bestScore = -1;
    int bsel[4] = {0,1,2,3}; int bT0 = 4, bT1 = 5; int bperm[4] = {0,1,2,3};
    int cand = 0;
    for (int a = 0; a < 8; ++a) for (int b = a + 1; b < 8; ++b)
    for (int c = b + 1; c < 8; ++c) for (int d = c + 1; d < 8; ++d) {
      uint32_t jc[4] = {Bc[np0[a]], Bc[np0[b]], Bc[np0[c]], Bc[np0[d]]};
      int rJ = rank5(jc, 4);
      if (rJ < 4 && bestScore >= 0) continue;
      if (rJ == 4) { if (cand >= 4) continue; ++cand; }
      int rem[4] = {}; int rc2 = 0;
      for (int q = 0; q < 8; ++q) if (q != a && q != b && q != c && q != d) rem[rc2++] = q;
      const int tmax = (p == 5) ? 4 : 1;  // only pass5 cares which free bits are T
      for (int t0 = 0; t0 < tmax; ++t0) for (int t1 = 0; t1 < tmax; ++t1) {
        if (p != 5) { if (t0 != 0 || t1 != 0) continue; }
        else if (t1 == t0) continue;
        const int rt0 = (p == 5) ? t0 : 0, rt1 = (p == 5) ? t1 : 1;
        for (int pa = 0; pa < 4; ++pa) for (int pb2 = 0; pb2 < 4; ++pb2) {
          if (pb2 == pa) continue;
          for (int pc = 0; pc < 4; ++pc) {
            if (pc == pa || pc == pb2) continue;
            const int pd = 6 - pa - pb2 - pc;
            uint32_t rd[6] = {jc[0], jc[1], jc[2], jc[3], v0[pc], v0[pd]};   // reads vary g -> v2,v3
            int rR = rank5(rd, 6);
            uint32_t wr[6] = {jc[0], jc[1], jc[2], jc[3], v0[pb2], v0[pc]};  // writes vary g -> v1,v2
            int rW = rank5(wr, 6);
            int rRO = 0;
            if (p == 5) {
              uint32_t roc[6] = {jc[0], jc[1], jc[2], jc[3], Bc[np0[rem[rt0]]], Bc[np0[rem[rt1]]]};
              rRO = rank5(roc, 6);
            }
            int score = rJ * 1000 + (rR == 5 ? 100 : 0) + (rW == 5 ? 10 : 0)
                      + (p == 5 ? (rRO == 5 ? 1 : 0) : 0);
            if (score > bestScore) {
              bestScore = score;
              bsel[0] = a; bsel[1] = b; bsel[2] = c; bsel[3] = d;
              bT0 = rem[rt0]; bT1 = rem[rt1];
              bperm[0] = pa; bperm[1] = pb2; bperm[2] = pc; bperm[3] = pd;
            }
          }
        }
      }
    }
    // fill np: [0..3]=j, [4..5]=T, [6..7]=rest
    uint8_t npn[8] = {};
    npn[0] = np0[bsel[0]]; npn[1] = np0[bsel[1]];
    npn[2] = np0[bsel[2]]; npn[3] = np0[bsel[3]];
    npn[4] = np0[bT0]; npn[5] = np0[bT1];
    int cn = 6;
    for (int q = 0; q < 8; ++q) {
      bool used = (q == bsel[0] || q == bsel[1] || q == bsel[2] || q == bsel[3] ||
                   q == bT0 || q == bT1);
      if (!used) npn[cn++] = np0[q];
    }
    for (int q = 0; q < 8; ++q) kp.pass[p].np[q] = npn[q];
    for (int i = 0; i < 4; ++i) {
      kp.pass[p].v[i] = (uint16_t)v0[bperm[i]];
      kp.pass[p].m[i] = (uint16_t)m0[bperm[i]];
      kp.pass[p].wire[i] = (uint8_t)(wb + bperm[i]);
    }
    kp.pass[p].td[0] = 0;
    kp.pass[p].td[1] = (uint16_t)Bc[npn[4]];
    kp.pass[p].td[2] = (uint16_t)Bc[npn[5]];
    kp.pass[p].td[3] = (uint16_t)(Bc[npn[4]] ^ Bc[npn[5]]);
    kp.pass[p].layer = (uint8_t)L;
    if (p == 5) {
      v5_0 = v0[bperm[0]]; v5_3 = v0[bperm[3]];
      td5_1 = Bc[npn[4]]; td5_2 = Bc[npn[5]];
    }
  }
  for (int i = 0; i < NQ; ++i) kp.ro_mask[i] = (uint16_t)A3[i];
  for (int i = 0; i < NQ; ++i) {
    uint32_t b = 0;
    b |= (uint32_t)(__builtin_popcount(A3[i] & v5_0) & 1) << 0;
    b |= (uint32_t)(__builtin_popcount(A3[i] & v5_3) & 1) << 1;
    b |= (uint32_t)(__builtin_popcount(A3[i] & td5_1) & 1) << 2;
    b |= (uint32_t)(__builtin_popcount(A3[i] & td5_2) & 1) << 3;
    kp.ro_bin[i] = (uint8_t)b;
  }
  return kp;
}

constexpr KP kpc = make_kp();

// ---------- device helpers ----------
__device__ __forceinline__ v2f cmulf(v2f a, v2f b) {
  return (v2f){a.x * b.x - a.y * b.y, a.x * b.y + a.y * b.x};
}
__device__ __forceinline__ uint32_t f2h2(float a, float b) {
  return __builtin_bit_cast(uint32_t, __builtin_amdgcn_cvt_pkrtz(a, b));
}
__device__ __forceinline__ uint32_t pk_rtn(float a, float b) {
  v2h h = {(_Float16)a, (_Float16)b};   // RTN converts for the gate matrix
  return __builtin_bit_cast(uint32_t, h);
}

__device__ __forceinline__ void build_u(const float* __restrict__ qp, int l, int w, float U[8]) {
  float p0 = qp[(l * 12 + w) * 3 + 0];
  float p1 = qp[(l * 12 + w) * 3 + 1];
  float p2 = qp[(l * 12 + w) * 3 + 2];
  float cx, sx, cy, sy, cz, sz;
  sincosf(0.5f * p0, &sx, &cx);
  sincosf(0.5f * p1, &sy, &cy);
  sincosf(0.5f * p2, &sz, &cz);
  float M00x =  cy * cx, M00y =  sy * sx;
  float M01x = -sy * cx, M01y = -cy * sx;
  float M10x =  sy * cx, M10y = -cy * sx;
  float M11x =  cy * cx, M11y = -sy * sx;
  U[0] = cz * M00x + sz * M00y; U[1] = cz * M00y - sz * M00x;
  U[2] = cz * M01x + sz * M01y; U[3] = cz * M01y - sz * M01x;
  U[4] = cz * M10x - sz * M10y; U[5] = cz * M10y + sz * M10x;
  U[6] = cz * M11x - sz * M11y; U[7] = cz * M11y + sz * M11x;
}

// Am column swizzle (quad-granular, keeps b128 contiguity, spreads banks)
__device__ __forceinline__ int am_col(int c, int i) {
  return ((((c >> 2) ^ ((i >> 1) & 3)) << 2) | (c & 3));
}

// ---------- per-pass MFMA engine ----------
template<int P, bool LAST>
__device__ __forceinline__ void do_pass(uint32_t* st, f16x8 a0, f16x8 a1,
                                        int lane, int wv, float* ev) {
  constexpr PassP pp = kpc.pass[P];
  const int t6 = (lane & 15) | (wv << 6);
  int rep = 0;
  #pragma unroll
  for (int k = 0; k < 8; ++k) rep |= ((t6 >> k) & 1) << pp.np[k];
  int base = rep;
  #pragma unroll
  for (int i = 0; i < 4; ++i)
    if (__popc(pp.m[i] & rep) & 1) base ^= pp.v[i];
  const int g = lane >> 4;
  const int cgr = ((g & 1) ? pp.v[2] : 0) ^ ((g & 2) ? pp.v[3] : 0);
  const int cgw = ((g & 1) ? pp.v[1] : 0) ^ ((g & 2) ? pp.v[2] : 0);
  float pr[16];
  const f32x4 z = {0.f, 0.f, 0.f, 0.f};
  #pragma unroll
  for (int T = 0; T < 4; ++T) {
    const int bT = base ^ pp.td[T];
    const int ra = bT ^ cgr;
    u32x4 braw = { st[ra], st[ra ^ pp.v[0]], st[ra ^ pp.v[1]],
                   st[ra ^ (pp.v[0] ^ pp.v[1])] };
    f16x8 bf = __builtin_bit_cast(f16x8, braw);
    f32x4 c0 = __builtin_amdgcn_mfma_f32_16x16x32_f16(a0, bf, z, 0, 0, 0);
    f32x4 c1 = __builtin_amdgcn_mfma_f32_16x16x32_f16(a1, bf, z, 0, 0, 0);
    if constexpr (!LAST) {
      const int wa = bT ^ cgw;
      st[wa]                      = f2h2(c0.x, c0.y);
      st[wa ^ pp.v[0]]            = f2h2(c0.z, c0.w);
      st[wa ^ pp.v[3]]            = f2h2(c1.x, c1.y);
      st[wa ^ (pp.v[3] ^ pp.v[0])] = f2h2(c1.z, c1.w);
    } else {
      const int nb = ((T & 1) << 2) | ((T >> 1) << 3);
      pr[nb]     = c0.x * c0.x + c0.y * c0.y;
      pr[nb | 1] = c0.z * c0.z + c0.w * c0.w;
      pr[nb | 2] = c1.x * c1.x + c1.y * c1.y;
      pr[nb | 3] = c1.z * c1.z + c1.w * c1.w;
    }
  }
  if constexpr (LAST) {
    // 4-dim WHT over lane's affine span {v0, v3, td1, td2}
    #pragma unroll
    for (int gs = 1; gs < 16; gs <<= 1) {
      #pragma unroll
      for (int j = 0; j < 16; ++j) {
        if (j & gs) continue;
        float u = pr[j], w2 = pr[j | gs];
        pr[j] = u + w2; pr[j | gs] = u - w2;
      }
    }
    const int baseL = base ^ cgw;
    #pragma unroll
    for (int i = 0; i < NQ; ++i) {
      float h = pr[kpc.ro_bin[i]];
      int s = (__popc(kpc.ro_mask[i] & baseL) & 1) << 31;
      ev[i] = __int_as_float(__float_as_int(h) ^ s);
    }
  }
}

// ---------- kernel ----------
__global__ __launch_bounds__(TPB, 5) void hqc_kernel(
    const float* __restrict__ x,  const float* __restrict__ W1, const float* __restrict__ b1,
    const float* __restrict__ W2, const float* __restrict__ b2,
    const float* __restrict__ W3, const float* __restrict__ b3,
    const float* __restrict__ qp, const float* __restrict__ P1, const float* __restrict__ c1,
    const float* __restrict__ P2, const float* __restrict__ c2,
    const float* __restrict__ P3, const float* __restrict__ c3,
    float* __restrict__ out)
{
  __shared__ uint32_t st[DIM];                       // 16 KB packed-half2 state
  __shared__ __align__(16) uint32_t Am[6][32][16];   // 12 KB: 6 real-rep f16 matrices
  __shared__ v2f  gg[2][12][4];                      // layer1/2 gates (complex)
  __shared__ v4f  gpk0[12][2];                       // L0-folded columns {x,x,-y,y}
  __shared__ float red[4][NQ];

  const int s    = blockIdx.x;
  const int t    = threadIdx.x;
  const int lane = t & 63;
  const int wv   = t >> 6;
  const int g    = lane >> 4;

  // ---- phase 0a: wave0 = MLP + L0-folded gates; waves1/2 = layer gates ----
  if (wv == 0) {
    if (lane < 16) {
      float a = b1[lane];
      #pragma unroll
      for (int k = 0; k < 6; ++k) a = fmaf(W1[lane * 6 + k], x[s * 6 + k], a);
      float h1 = fmaxf(a, 0.f);
      float a2 = b2[lane];
      #pragma unroll
      for (int k = 0; k < 16; ++k) a2 = fmaf(W2[lane * 16 + k], __shfl(h1, k, 64), a2);
      float h2 = fmaxf(a2, 0.f);
      const int lw = (lane < NQ) ? lane : 0;
      float a3 = b3[lw];
      #pragma unroll
      for (int k = 0; k < 16; ++k) a3 = fmaf(W3[lw * 16 + k], __shfl(h2, k, 64), a3);
      if (lane < NQ) {
        float U[8]; build_u(qp, 0, lane, U);
        float ca, sa; sincosf(0.5f * a3, &sa, &ca);
        float c0x = U[0] * ca + U[2] * sa, c0y = U[1] * ca + U[3] * sa;
        float c1x = U[4] * ca + U[6] * sa, c1y = U[5] * ca + U[7] * sa;
        gpk0[lane][0] = (v4f){c0x, c0x, -c0y, c0y};
        gpk0[lane][1] = (v4f){c1x, c1x, -c1y, c1y};
      }
    }
  } else if (wv <= 2) {
    if (lane < NQ) {
      float U[8]; build_u(qp, wv, lane, U);
      gg[wv - 1][lane][0] = (v2f){U[0], U[1]};
      gg[wv - 1][lane][1] = (v2f){U[2], U[3]};
      gg[wv - 1][lane][2] = (v2f){U[4], U[5]};
      gg[wv - 1][lane][3] = (v2f){U[6], U[7]};
    }
  }
  __syncthreads();

  // ---- phase 0b: build the 6 real-rep f16 kron matrices (1 entry/thread/pass) ----
  {
    const int r_ = t >> 4, c_ = t & 15;
    #pragma unroll
    for (int p = 0; p < 6; ++p) {
      v2f e = (v2f){1.f, 0.f};
      #pragma unroll
      for (int i = 0; i < 4; ++i) {
        v2f u = gg[kpc.pass[p].layer - 1][kpc.pass[p].wire[i]]
                  [(((r_ >> i) & 1) << 1) | ((c_ >> i) & 1)];
        e = cmulf(e, u);
      }
      const int i0 = 2 * r_, i1 = 2 * r_ + 1;
      Am[p][i0][am_col(c_, i0)] = pk_rtn(e.x, -e.y);
      Am[p][i1][am_col(c_, i1)] = pk_rtn(e.y, e.x);
    }
  }

  // ---- product-state init (writes st; barrier below covers Am too) ----
  {
    v2f acc = (v2f){1.f, 0.f};
    #pragma unroll
    for (int i = 0; i < 8; ++i) {
      v4f gk = gpk0[i][(t >> i) & 1];
      acc = gk.xy * acc + gk.zw * acc.yx;
    }
    v2f l16[16];
    l16[0] = acc;
    #pragma unroll
    for (int i = 0; i < 4; ++i) {
      v4f g0 = gpk0[8 + i][0], g1 = gpk0[8 + i][1];
      #pragma unroll
      for (int j = 0; j < (1 << i); ++j) {
        v2f a = l16[j];
        l16[j | (1 << i)] = g1.xy * a + g1.zw * a.yx;
        l16[j]            = g0.xy * a + g0.zw * a.yx;
      }
    }
    #pragma unroll
    for (int j = 0; j < 16; ++j) st[t | (j << 8)] = f2h2(l16[j].x, l16[j].y);
  }
  __syncthreads();

  // ---- preload A-fragments (48 VGPRs, live through all passes) ----
  f16x8 af[6][2];
  #pragma unroll
  for (int p = 0; p < 6; ++p) {
    #pragma unroll
    for (int Rb = 0; Rb < 2; ++Rb) {
      const int i = Rb * 16 + (lane & 15);
      const int q = g ^ ((i >> 1) & 3);
      const u32x4* src = reinterpret_cast<const u32x4*>(&Am[p][i][q * 4]);
      af[p][Rb] = __builtin_bit_cast(f16x8, *src);
    }
  }

  float ev[NQ];
  do_pass<0, false>(st, af[0][0], af[0][1], lane, wv, ev); __syncthreads();
  do_pass<1, false>(st, af[1][0], af[1][1], lane, wv, ev); __syncthreads();
  do_pass<2, false>(st, af[2][0], af[2][1], lane, wv, ev); __syncthreads();
  do_pass<3, false>(st, af[3][0], af[3][1], lane, wv, ev); __syncthreads();
  do_pass<4, false>(st, af[4][0], af[4][1], lane, wv, ev); __syncthreads();
  do_pass<5, true >(st, af[5][0], af[5][1], lane, wv, ev);  // fused readout

  // ---- reduce 12 evs across lanes, then waves ----
  #pragma unroll
  for (int off = 32; off >= 1; off >>= 1) {
    #pragma unroll
    for (int i = 0; i < NQ; ++i) ev[i] += __shfl_xor(ev[i], off, 64);
  }
  if (lane == 0) {
    #pragma unroll
    for (int i = 0; i < NQ; ++i) red[wv][i] = ev[i];
  }
  __syncthreads();

  // ---- post-MLP on wave 0 via shuffles ----
  if (wv == 0 && lane < 16) {
    float q = (lane < NQ)
      ? (red[0][lane] + red[1][lane] + red[2][lane] + red[3][lane])
      : 0.f;
    float a = c1[lane];
    #pragma unroll
    for (int j = 0; j < NQ; ++j) a = fmaf(P1[lane * NQ + j], __shfl(q, j, 64), a);
    float o1 = fmaxf(a, 0.f);
    float a2 = c2[lane & 7];
    #pragma unroll
    for (int j = 0; j < 16; ++j) a2 = fmaf(P2[(lane & 7) * 16 + j], __shfl(o1, j, 64), a2);
    float o2 = fmaxf(a2, 0.f);
    float a3 = c3[0];
    #pragma unroll
    for (int j = 0; j < 8; ++j) a3 = fmaf(P3[j], __shfl(o2, j, 64), a3);
    if (lane == 0) out[s] = 1.f / (1.f + expf(-a3));
  }
}

extern "C" void kernel_launch(void* const* d_in, const int* in_sizes, int n_in,
                              void* d_out, int out_size, void* d_ws, size_t ws_size,
                              hipStream_t stream) {
  (void)in_sizes; (void)n_in; (void)d_ws; (void)ws_size;
  hqc_kernel<<<out_size, TPB, 0, stream>>>(
      (const float*)d_in[0],  (const float*)d_in[1],  (const float*)d_in[2],
      (const float*)d_in[3],  (const float*)d_in[4],  (const float*)d_in[5],
      (const float*)d_in[6],  (const float*)d_in[7],  (const float*)d_in[8],
      (const float*)d_in[9],  (const float*)d_in[10], (const float*)d_in[11],
      (const float*)d_in[12], (const float*)d_in[13],
      (float*)d_out);
}

// Round 8
// 54.363 us; speedup vs baseline: 2.3687x; 1.0608x over previous
//
#include <hip/hip_runtime.h>
#include <stdint.h>

#define NQ   12
#define DIM  4096   // 2^12 amplitudes
#define TPB  256

typedef float   v2f   __attribute__((ext_vector_type(2)));
typedef float   v4f   __attribute__((ext_vector_type(4)));
typedef float   f32x4 __attribute__((ext_vector_type(4)));
typedef _Float16 v2h  __attribute__((ext_vector_type(2)));
typedef _Float16 f16x8 __attribute__((ext_vector_type(8)));
typedef uint32_t u32x4 __attribute__((ext_vector_type(4)));

// ---------- compile-time GF(2) circuit structure ----------
struct PassP {
  uint16_t v[4];    // pair XOR-vectors (permuted order: bit i of r <-> v[i])
  uint16_t m[4];    // role parity masks (permuted to match v)
  uint16_t td[4];   // baseT deltas (B * T-bit columns)
  uint8_t  np[8];   // free-bit slots: [0..3]=j, [4..5]=T, [6..7]=wave
  uint8_t  wire[4]; // absolute wire index for r-bit i
  uint8_t  layer;   // 1 or 2
  uint8_t  pad[3];
};
struct ROC {
  uint16_t mask[12]; // rows of A^3
  uint8_t  bin[12];  // WHT bin per qubit over pass5 lane-span {v0,v3,td1,td2}
};

constexpr int chbit(uint32_t x) { int b = -1; for (int i = 0; i < 32; ++i) if ((x >> i) & 1u) b = i; return b; }

constexpr void bmm(uint32_t* C, const uint32_t* A, const uint32_t* B) {
  for (int i = 0; i < NQ; ++i) {
    uint32_t r = 0;
    for (int j = 0; j < NQ; ++j) if ((A[i] >> j) & 1u) r ^= B[j];
    C[i] = r;
  }
}
constexpr void binv(const uint32_t* M, uint32_t* Inv) {
  uint32_t A[NQ] = {}, I[NQ] = {};
  for (int i = 0; i < NQ; ++i) { A[i] = M[i]; I[i] = 1u << i; }
  for (int c = 0; c < NQ; ++c) {
    int piv = -1;
    for (int r = c; r < NQ; ++r) if ((A[r] >> c) & 1u) { piv = r; break; }
    if (piv < 0) continue;
    uint32_t ta = A[c]; A[c] = A[piv]; A[piv] = ta;
    uint32_t ti = I[c]; I[c] = I[piv]; I[piv] = ti;
    for (int r = 0; r < NQ; ++r)
      if (r != c && ((A[r] >> c) & 1u)) { A[r] ^= A[c]; I[r] ^= I[c]; }
  }
  for (int i = 0; i < NQ; ++i) Inv[i] = I[i];
}

constexpr int rank5(const uint32_t* cols, int n) {
  uint32_t rows[5] = {}; int rnk = 0;
  for (int q = 0; q < n; ++q) {
    uint32_t x = cols[q] & 31u;
    for (int bit = 4; bit >= 0; --bit) {
      if (!((x >> bit) & 1u)) continue;
      if (rows[bit]) { x ^= rows[bit]; }
      else { rows[bit] = x; ++rnk; break; }
    }
  }
  return rnk;
}
// measured LDS conflict penalty (m136): rank5 -> 2 lanes/bank (free),
// rank4 -> 4-way (1.58x), rank3 -> 8-way (2.94x), rank2 -> 16-way (5.69x)
constexpr int penalty(int r) {
  return r >= 5 ? 0 : r == 4 ? 58 : r == 3 ? 194 : r == 2 ? 469 : 1100;
}

// One pass's structure; a SEPARATE constexpr evaluation per pass keeps each
// under clang's constexpr step limit (round-7 lesson: one big make_kp() blew it).
constexpr PassP make_pass(int p) {
  PassP pp{};
  uint32_t A[NQ] = {}; A[0] = 0xFFEu;
  for (int i = 1; i < NQ; ++i) A[i] = (1u << (i + 1)) - 1u;
  uint32_t A2[NQ] = {}, Ai[NQ] = {}, A2i[NQ] = {};
  bmm(A2, A, A);
  binv(A, Ai); binv(A2, A2i);

  const int L = (p < 3) ? 1 : 2;
  const int wb = (p % 3) * 4;
  const uint32_t* M  = (L == 1) ? A  : A2;
  const uint32_t* Mi = (L == 1) ? Ai : A2i;
  uint32_t v0[4] = {}, m0[4] = {};
  for (int i = 0; i < 4; ++i) {
    int w = wb + i; uint32_t col = 0;
    for (int r = 0; r < NQ; ++r) col |= ((Mi[r] >> w) & 1u) << r;
    v0[i] = col; m0[i] = M[w];
  }
  // B = I ^ sum v_i m_i^T (perm-invariant); columns:
  uint32_t Bc[NQ] = {};
  for (int b = 0; b < NQ; ++b) {
    uint32_t col = 1u << b;
    for (int i = 0; i < 4; ++i) if ((m0[i] >> b) & 1u) col ^= v0[i];
    Bc[b] = col;
  }
  // free (non-pivot) bits of span{v}
  uint32_t redv[4] = {}; int pbit[4] = {}; uint32_t pivmask = 0;
  for (int i = 0; i < 4; ++i) {
    redv[i] = v0[i];
    for (int k2 = 0; k2 < i; ++k2) if ((redv[i] >> pbit[k2]) & 1u) redv[i] ^= redv[k2];
    pbit[i] = chbit(redv[i]); pivmask |= 1u << pbit[i];
  }
  uint8_t np0[8] = {}; int nc = 0;
  for (int b = 0; b < NQ; ++b) if (!((pivmask >> b) & 1u)) np0[nc++] = (uint8_t)b;

  // exhaustive search: j-slot selection C(8,4) x pair-vector permutation S4,
  // minimizing measured bank-conflict cost. Read span = jc u {v_pc, v_pd};
  // write span = jc u {v_pb, v_pc} -- both "jc u unordered v-pair", so
  // precompute the 6 pair-ranks per j-set and the perm loop is O(1) lookups.
  int bestCost = 1 << 30;
  int bsel[4] = {0, 1, 2, 3}; int bperm[4] = {0, 1, 2, 3};
  for (int a = 0; a < 8; ++a) for (int b = a + 1; b < 8; ++b)
  for (int c = b + 1; c < 8; ++c) for (int d = c + 1; d < 8; ++d) {
    uint32_t jc[4] = {Bc[np0[a]], Bc[np0[b]], Bc[np0[c]], Bc[np0[d]]};
    int prk[4][4] = {};
    for (int i = 0; i < 4; ++i)
      for (int j = i + 1; j < 4; ++j) {
        uint32_t sp[6] = {jc[0], jc[1], jc[2], jc[3], v0[i], v0[j]};
        prk[i][j] = prk[j][i] = rank5(sp, 6);
      }
    for (int pa = 0; pa < 4; ++pa) for (int pb2 = 0; pb2 < 4; ++pb2) {
      if (pb2 == pa) continue;
      for (int pc = 0; pc < 4; ++pc) {
        if (pc == pa || pc == pb2) continue;
        const int pd = 6 - pa - pb2 - pc;
        const int cost = penalty(prk[pc][pd]) + penalty(prk[pb2][pc]);
        if (cost < bestCost) {
          bestCost = cost;
          bsel[0] = a; bsel[1] = b; bsel[2] = c; bsel[3] = d;
          bperm[0] = pa; bperm[1] = pb2; bperm[2] = pc; bperm[3] = pd;
        }
      }
    }
  }
  // T slots = first two remaining free bits
  int rem[4] = {}; int rc2 = 0;
  for (int q = 0; q < 8; ++q)
    if (q != bsel[0] && q != bsel[1] && q != bsel[2] && q != bsel[3]) rem[rc2++] = q;

  uint8_t npn[8] = {};
  npn[0] = np0[bsel[0]]; npn[1] = np0[bsel[1]];
  npn[2] = np0[bsel[2]]; npn[3] = np0[bsel[3]];
  npn[4] = np0[rem[0]]; npn[5] = np0[rem[1]];
  npn[6] = np0[rem[2]]; npn[7] = np0[rem[3]];
  for (int q = 0; q < 8; ++q) pp.np[q] = npn[q];
  for (int i = 0; i < 4; ++i) {
    pp.v[i] = (uint16_t)v0[bperm[i]];
    pp.m[i] = (uint16_t)m0[bperm[i]];
    pp.wire[i] = (uint8_t)(wb + bperm[i]);
  }
  pp.td[0] = 0;
  pp.td[1] = (uint16_t)Bc[npn[4]];
  pp.td[2] = (uint16_t)Bc[npn[5]];
  pp.td[3] = (uint16_t)(Bc[npn[4]] ^ Bc[npn[5]]);
  pp.layer = (uint8_t)L;
  return pp;
}

constexpr PassP kp0 = make_pass(0);
constexpr PassP kp1 = make_pass(1);
constexpr PassP kp2 = make_pass(2);
constexpr PassP kp3 = make_pass(3);
constexpr PassP kp4 = make_pass(4);
constexpr PassP kp5 = make_pass(5);

template<int P>
constexpr PassP pget() {
  if constexpr (P == 0) return kp0;
  else if constexpr (P == 1) return kp1;
  else if constexpr (P == 2) return kp2;
  else if constexpr (P == 3) return kp3;
  else if constexpr (P == 4) return kp4;
  else return kp5;
}

constexpr ROC make_ro() {
  ROC r{};
  uint32_t A[NQ] = {}; A[0] = 0xFFEu;
  for (int i = 1; i < NQ; ++i) A[i] = (1u << (i + 1)) - 1u;
  uint32_t A2[NQ] = {}, A3[NQ] = {};
  bmm(A2, A, A); bmm(A3, A2, A);
  for (int i = 0; i < NQ; ++i) r.mask[i] = (uint16_t)A3[i];
  for (int i = 0; i < NQ; ++i) {
    uint32_t b = 0;
    b |= (uint32_t)(__builtin_popcount(A3[i] & (uint32_t)kp5.v[0]) & 1) << 0;
    b |= (uint32_t)(__builtin_popcount(A3[i] & (uint32_t)kp5.v[3]) & 1) << 1;
    b |= (uint32_t)(__builtin_popcount(A3[i] & (uint32_t)kp5.td[1]) & 1) << 2;
    b |= (uint32_t)(__builtin_popcount(A3[i] & (uint32_t)kp5.td[2]) & 1) << 3;
    r.bin[i] = (uint8_t)b;
  }
  return r;
}
constexpr ROC roc = make_ro();

// ---------- device helpers ----------
__device__ __forceinline__ v2f cmulf(v2f a, v2f b) {
  return (v2f){a.x * b.x - a.y * b.y, a.x * b.y + a.y * b.x};
}
__device__ __forceinline__ uint32_t f2h2(float a, float b) {
  return __builtin_bit_cast(uint32_t, __builtin_amdgcn_cvt_pkrtz(a, b));
}
__device__ __forceinline__ uint32_t pk_rtn(float a, float b) {
  v2h h = {(_Float16)a, (_Float16)b};
  return __builtin_bit_cast(uint32_t, h);
}

__device__ __forceinline__ void build_u(const float* __restrict__ qp, int l, int w, float U[8]) {
  float p0 = qp[(l * 12 + w) * 3 + 0];
  float p1 = qp[(l * 12 + w) * 3 + 1];
  float p2 = qp[(l * 12 + w) * 3 + 2];
  float cx, sx, cy, sy, cz, sz;
  sincosf(0.5f * p0, &sx, &cx);
  sincosf(0.5f * p1, &sy, &cy);
  sincosf(0.5f * p2, &sz, &cz);
  float M00x =  cy * cx, M00y =  sy * sx;
  float M01x = -sy * cx, M01y = -cy * sx;
  float M10x =  sy * cx, M10y = -cy * sx;
  float M11x =  cy * cx, M11y = -sy * sx;
  U[0] = cz * M00x + sz * M00y; U[1] = cz * M00y - sz * M00x;
  U[2] = cz * M01x + sz * M01y; U[3] = cz * M01y - sz * M01x;
  U[4] = cz * M10x - sz * M10y; U[5] = cz * M10y + sz * M10x;
  U[6] = cz * M11x - sz * M11y; U[7] = cz * M11y + sz * M11x;
}

// Am column swizzle (quad-granular, keeps b128 contiguity, spreads banks)
__device__ __forceinline__ int am_col(int c, int i) {
  return ((((c >> 2) ^ ((i >> 1) & 3)) << 2) | (c & 3));
}

// build the real-rep f16 kron matrix for pass P into Am2[P&1] (1 cplx entry/thread)
template<int P>
__device__ __forceinline__ void build_am(uint32_t (*Am2)[32][16],
                                         const v2f (*gg)[12][4], int t) {
  constexpr PassP pp = pget<P>();
  const int r_ = t >> 4, c_ = t & 15;
  v2f e = (v2f){1.f, 0.f};
  #pragma unroll
  for (int i = 0; i < 4; ++i) {
    v2f u = gg[pp.layer - 1][pp.wire[i]][(((r_ >> i) & 1) << 1) | ((c_ >> i) & 1)];
    e = cmulf(e, u);
  }
  const int ra = 2 * r_, rb = 2 * r_ + 1;
  Am2[P & 1][ra][am_col(c_, ra)] = pk_rtn(e.x, -e.y);
  Am2[P & 1][rb][am_col(c_, rb)] = pk_rtn(e.y, e.x);
}

// ---------- per-pass MFMA engine ----------
template<int P, bool LAST>
__device__ __forceinline__ void do_pass(uint32_t* st, uint32_t (*Am2)[32][16],
                                        const v2f (*gg)[12][4], int t, float* ev) {
  constexpr PassP pp = pget<P>();
  const int lane = t & 63;
  const int wv   = t >> 6;
  const int g    = lane >> 4;
  // A-fragments for this pass (reloaded per pass from the 2KB staging buffer)
  f16x8 a0, a1;
  {
    const int li = lane & 15;
    const int q0 = g ^ ((li >> 1) & 3);
    a0 = __builtin_bit_cast(f16x8, *reinterpret_cast<const u32x4*>(&Am2[P & 1][li][q0 * 4]));
    const int i1 = 16 + li;
    const int q1 = g ^ ((i1 >> 1) & 3);
    a1 = __builtin_bit_cast(f16x8, *reinterpret_cast<const u32x4*>(&Am2[P & 1][i1][q1 * 4]));
  }
  const int t6 = (lane & 15) | (wv << 6);
  int rep = 0;
  #pragma unroll
  for (int k = 0; k < 8; ++k) rep |= ((t6 >> k) & 1) << pp.np[k];
  int base = rep;
  #pragma unroll
  for (int i = 0; i < 4; ++i)
    if (__popc(pp.m[i] & rep) & 1) base ^= pp.v[i];
  const int cgr = ((g & 1) ? pp.v[2] : 0) ^ ((g & 2) ? pp.v[3] : 0);
  const int cgw = ((g & 1) ? pp.v[1] : 0) ^ ((g & 2) ? pp.v[2] : 0);
  float pr[16];
  const f32x4 z = {0.f, 0.f, 0.f, 0.f};
  #pragma unroll
  for (int T = 0; T < 4; ++T) {
    const int bT = base ^ pp.td[T];
    const int ra = bT ^ cgr;
    u32x4 braw = { st[ra], st[ra ^ pp.v[0]], st[ra ^ pp.v[1]],
                   st[ra ^ (pp.v[0] ^ pp.v[1])] };
    f16x8 bf = __builtin_bit_cast(f16x8, braw);
    f32x4 c0 = __builtin_amdgcn_mfma_f32_16x16x32_f16(a0, bf, z, 0, 0, 0);
    f32x4 c1 = __builtin_amdgcn_mfma_f32_16x16x32_f16(a1, bf, z, 0, 0, 0);
    if constexpr (!LAST) {
      const int wa = bT ^ cgw;
      st[wa]                       = f2h2(c0.x, c0.y);
      st[wa ^ pp.v[0]]             = f2h2(c0.z, c0.w);
      st[wa ^ pp.v[3]]             = f2h2(c1.x, c1.y);
      st[wa ^ (pp.v[3] ^ pp.v[0])] = f2h2(c1.z, c1.w);
    } else {
      const int nb = ((T & 1) << 2) | ((T >> 1) << 3);
      pr[nb]     = c0.x * c0.x + c0.y * c0.y;
      pr[nb | 1] = c0.z * c0.z + c0.w * c0.w;
      pr[nb | 2] = c1.x * c1.x + c1.y * c1.y;
      pr[nb | 3] = c1.z * c1.z + c1.w * c1.w;
    }
  }
  if constexpr (P < 5) build_am<P + 1>(Am2, gg, t);   // stage next pass's matrix
  if constexpr (LAST) {
    // 4-dim WHT over lane's affine span {v0, v3, td1, td2}
    #pragma unroll
    for (int gs = 1; gs < 16; gs <<= 1) {
      #pragma unroll
      for (int j = 0; j < 16; ++j) {
        if (j & gs) continue;
        float u = pr[j], w2 = pr[j | gs];
        pr[j] = u + w2; pr[j | gs] = u - w2;
      }
    }
    const int baseL = base ^ cgw;
    #pragma unroll
    for (int i = 0; i < NQ; ++i) {
      float h = pr[roc.bin[i]];
      int s = (__popc(roc.mask[i] & baseL) & 1) << 31;
      ev[i] = __int_as_float(__float_as_int(h) ^ s);
    }
  }
}

// ---------- kernel ----------
__global__ __launch_bounds__(TPB, 7) void hqc_kernel(
    const float* __restrict__ x,  const float* __restrict__ W1, const float* __restrict__ b1,
    const float* __restrict__ W2, const float* __restrict__ b2,
    const float* __restrict__ W3, const float* __restrict__ b3,
    const float* __restrict__ qp, const float* __restrict__ P1, const float* __restrict__ c1,
    const float* __restrict__ P2, const float* __restrict__ c2,
    const float* __restrict__ P3, const float* __restrict__ c3,
    float* __restrict__ out)
{
  __shared__ uint32_t st[DIM];                        // 16 KB packed-half2 state
  __shared__ __align__(16) uint32_t Am2[2][32][16];   // 4 KB double-buffered pass matrix
  __shared__ v2f  gg[2][12][4];                       // layer1/2 gates (complex)
  __shared__ v4f  gpk0[12][2];                        // L0-folded columns {x,x,-y,y}
  __shared__ float red[4][NQ];

  const int s    = blockIdx.x;
  const int t    = threadIdx.x;
  const int lane = t & 63;
  const int wv   = t >> 6;

  // ---- phase 0a: wave0 = MLP + L0-folded gates; waves1/2 = layer gates ----
  if (wv == 0) {
    if (lane < 16) {
      float a = b1[lane];
      #pragma unroll
      for (int k = 0; k < 6; ++k) a = fmaf(W1[lane * 6 + k], x[s * 6 + k], a);
      float h1 = fmaxf(a, 0.f);
      float a2 = b2[lane];
      #pragma unroll
      for (int k = 0; k < 16; ++k) a2 = fmaf(W2[lane * 16 + k], __shfl(h1, k, 64), a2);
      float h2 = fmaxf(a2, 0.f);
      const int lw = (lane < NQ) ? lane : 0;
      float a3 = b3[lw];
      #pragma unroll
      for (int k = 0; k < 16; ++k) a3 = fmaf(W3[lw * 16 + k], __shfl(h2, k, 64), a3);
      if (lane < NQ) {
        float U[8]; build_u(qp, 0, lane, U);
        float ca, sa; sincosf(0.5f * a3, &sa, &ca);
        float c0x = U[0] * ca + U[2] * sa, c0y = U[1] * ca + U[3] * sa;
        float c1x = U[4] * ca + U[6] * sa, c1y = U[5] * ca + U[7] * sa;
        gpk0[lane][0] = (v4f){c0x, c0x, -c0y, c0y};
        gpk0[lane][1] = (v4f){c1x, c1x, -c1y, c1y};
      }
    }
  } else if (wv <= 2) {
    if (lane < NQ) {
      float U[8]; build_u(qp, wv, lane, U);
      gg[wv - 1][lane][0] = (v2f){U[0], U[1]};
      gg[wv - 1][lane][1] = (v2f){U[2], U[3]};
      gg[wv - 1][lane][2] = (v2f){U[4], U[5]};
      gg[wv - 1][lane][3] = (v2f){U[6], U[7]};
    }
  }
  __syncthreads();

  // ---- phase 0b: stage pass-0 matrix + product-state init ----
  build_am<0>(Am2, gg, t);
  {
    v2f acc = (v2f){1.f, 0.f};
    #pragma unroll
    for (int i = 0; i < 8; ++i) {
      v4f gk = gpk0[i][(t >> i) & 1];
      acc = gk.xy * acc + gk.zw * acc.yx;
    }
    v2f l16[16];
    l16[0] = acc;
    #pragma unroll
    for (int i = 0; i < 4; ++i) {
      v4f g0 = gpk0[8 + i][0], g1 = gpk0[8 + i][1];
      #pragma unroll
      for (int j = 0; j < (1 << i); ++j) {
        v2f a = l16[j];
        l16[j | (1 << i)] = g1.xy * a + g1.zw * a.yx;
        l16[j]            = g0.xy * a + g0.zw * a.yx;
      }
    }
    #pragma unroll
    for (int j = 0; j < 16; ++j) st[t | (j << 8)] = f2h2(l16[j].x, l16[j].y);
  }
  __syncthreads();

  float ev[NQ];
  do_pass<0, false>(st, Am2, gg, t, ev); __syncthreads();
  do_pass<1, false>(st, Am2, gg, t, ev); __syncthreads();
  do_pass<2, false>(st, Am2, gg, t, ev); __syncthreads();
  do_pass<3, false>(st, Am2, gg, t, ev); __syncthreads();
  do_pass<4, false>(st, Am2, gg, t, ev); __syncthreads();
  do_pass<5, true >(st, Am2, gg, t, ev);  // fused readout

  // ---- reduce 12 evs across lanes, then waves ----
  #pragma unroll
  for (int off = 32; off >= 1; off >>= 1) {
    #pragma unroll
    for (int i = 0; i < NQ; ++i) ev[i] += __shfl_xor(ev[i], off, 64);
  }
  if (lane == 0) {
    #pragma unroll
    for (int i = 0; i < NQ; ++i) red[wv][i] = ev[i];
  }
  __syncthreads();

  // ---- post-MLP on wave 0 via shuffles ----
  if (wv == 0 && lane < 16) {
    float q = (lane < NQ)
      ? (red[0][lane] + red[1][lane] + red[2][lane] + red[3][lane])
      : 0.f;
    float a = c1[lane];
    #pragma unroll
    for (int j = 0; j < NQ; ++j) a = fmaf(P1[lane * NQ + j], __shfl(q, j, 64), a);
    float o1 = fmaxf(a, 0.f);
    float a2 = c2[lane & 7];
    #pragma unroll
    for (int j = 0; j < 16; ++j) a2 = fmaf(P2[(lane & 7) * 16 + j], __shfl(o1, j, 64), a2);
    float o2 = fmaxf(a2, 0.f);
    float a3 = c3[0];
    #pragma unroll
    for (int j = 0; j < 8; ++j) a3 = fmaf(P3[j], __shfl(o2, j, 64), a3);
    if (lane == 0) out[s] = 1.f / (1.f + expf(-a3));
  }
}

extern "C" void kernel_launch(void* const* d_in, const int* in_sizes, int n_in,
                              void* d_out, int out_size, void* d_ws, size_t ws_size,
                              hipStream_t stream) {
  (void)in_sizes; (void)n_in; (void)d_ws; (void)ws_size;
  hqc_kernel<<<out_size, TPB, 0, stream>>>(
      (const float*)d_in[0],  (const float*)d_in[1],  (const float*)d_in[2],
      (const float*)d_in[3],  (const float*)d_in[4],  (const float*)d_in[5],
      (const float*)d_in[6],  (const float*)d_in[7],  (const float*)d_in[8],
      (const float*)d_in[9],  (const float*)d_in[10], (const float*)d_in[11],
      (const float*)d_in[12], (const float*)d_in[13],
      (float*)d_out);
}